// Round 1
// 3268.668 us; speedup vs baseline: 1.7382x; 1.7382x over previous
//
#include <hip/hip_runtime.h>

#define CDIV(a,b) (((a)+(b)-1)/(b))

typedef __attribute__((ext_vector_type(8))) short bf16x8;
typedef __attribute__((ext_vector_type(4))) float f32x4;

__device__ __forceinline__ short f2bf_rne(float x) {
    union { float f; unsigned u; } a; a.f = x;
    unsigned r = a.u + 0x7fffu + ((a.u >> 16) & 1u);
    return (short)(r >> 16);
}
__device__ __forceinline__ float bf2f(short h) {
    union { float f; unsigned u; } a; a.u = ((unsigned)(unsigned short)h) << 16;
    return a.f;
}

// ============ MFMA implicit-GEMM conv via bf16x3 split =======================
// out = relu(bias + inscale * conv(in, wt)); wt layout [Cout][cig][K][K]
// Tile: 128 cout x 128 spatial, 4 waves (2x2), per-wave 4x4 frags of 16x16.
// K-step 32 fp32 -> {hi,lo} bf16; acc += Ah*Bh + Ah*Bl + Al*Bh (fp32 MFMA acc).
// LDS fragment-major: tile t (0..7), lane (0..63), elem (0..7) -> contiguous
// 16B per lane => single ds_read_b128 per fragment. XOR-swizzle bits[6:4] by
// tile id to spread staging ds_write_b64 bank conflicts (reads: t uniform per
// wave => swizzle is a constant offset, pattern stays canonical/conflict-free).
template<int KSZ, int STRIDE, int PAD>
__global__ __launch_bounds__(256, 2) void conv_mfma128(
    const float* __restrict__ in, const float* __restrict__ wt,
    const float* __restrict__ bs, float* __restrict__ out,
    int N, int Cin, int Hin, int Win, int Cout, int groups,
    int Hout, int Wout, float inscale)
{
    const int cig = Cin / groups, cog = Cout / groups;
    const int R = cig * KSZ * KSZ;
    const int HW = Hout * Wout;
    const int NSP = N * HW;
    const int g = blockIdx.z;
    const int sp0 = blockIdx.x * 128;
    const int co0 = blockIdx.y * 128;
    const int tid = threadIdx.x;
    const int lane = tid & 63;
    const int wid = tid >> 6;
    const int wr = wid >> 1, wc = wid & 1;   // wave quadrant (cout-half, sp-half)

    __shared__ short Ah[4096], Al[4096], Bh[4096], Bl[4096];  // 8 KB each

    f32x4 acc[4][4];
    #pragma unroll
    for (int i = 0; i < 4; ++i)
        #pragma unroll
        for (int j = 0; j < 4; ++j)
            acc[i][j] = (f32x4){0.f, 0.f, 0.f, 0.f};

    // ---- A staging map: thread -> (cout' am, 16 consecutive k at ak0)
    const int am = tid >> 1;
    const int ak0 = (tid & 1) * 16;
    const bool wok = (co0 + am) < cog;
    const float* wrow = wt + (size_t)(g * cog + co0 + am) * R;
    const bool wvec = ((R & 3) == 0);      // float4-safe row start alignment
    const int aeb = (ak0 >> 4) * 4;        // elem base within fragment (0 or 4)
    const int amt = am >> 4;               // m-tile 0..7
    const int aml = am & 15;

    // ---- B staging map: thread -> (sp' n, 16 consecutive k at xk0)
    const int xn_ = tid & 127;
    const int xk0 = (tid >> 7) * 16;
    const int spx = sp0 + xn_;
    const bool xok = spx < NSP;
    int xn = 0, xho = 0, xwo = 0;
    if (xok) { xn = spx / HW; int pp = spx - xn * HW; xho = pp / Wout; xwo = pp - xho * Wout; }
    const float* inb = in + ((size_t)xn * Cin + (size_t)g * cig) * Hin * Win;
    const int hi0 = xho * STRIDE - PAD, wi0 = xwo * STRIDE - PAD;
    const int beb = (xk0 >> 4) * 4;
    const int bnt = xn_ >> 4;              // n-tile 0..7
    const int bnl = xn_ & 15;

    const int niter = (R + 31) / 32;
    for (int it = 0; it < niter; ++it) {
        const int r0 = it * 32;

        // ---- stage weights -> Ah/Al (fragment-major, hi/lo bf16)
        {
            float av[16];
            if (wvec && wok && (r0 + ak0 + 15) < R) {
                #pragma unroll
                for (int q4 = 0; q4 < 4; ++q4) {
                    float4 v = *(const float4*)(wrow + r0 + ak0 + q4 * 4);
                    av[q4 * 4 + 0] = v.x; av[q4 * 4 + 1] = v.y;
                    av[q4 * 4 + 2] = v.z; av[q4 * 4 + 3] = v.w;
                }
            } else {
                #pragma unroll
                for (int q = 0; q < 16; ++q) {
                    int r = r0 + ak0 + q;
                    av[q] = (wok && r < R) ? wrow[r] : 0.f;
                }
            }
            #pragma unroll
            for (int qq = 0; qq < 4; ++qq) {
                short hh[4], ll[4];
                #pragma unroll
                for (int j = 0; j < 4; ++j) {
                    float x = av[qq * 4 + j];
                    short h = f2bf_rne(x);
                    hh[j] = h;
                    ll[j] = f2bf_rne(x - bf2f(h));
                }
                int ln = aml + 16 * qq;
                int a = amt * 1024 + ln * 16 + aeb * 2;
                a ^= (amt & 7) << 4;
                *(short4*)((char*)Ah + a) = make_short4(hh[0], hh[1], hh[2], hh[3]);
                *(short4*)((char*)Al + a) = make_short4(ll[0], ll[1], ll[2], ll[3]);
            }
        }

        // ---- stage im2col patches -> Bh/Bl
        {
            float bv[16];
            #pragma unroll
            for (int q = 0; q < 16; ++q) {
                int r = r0 + xk0 + q;
                float v = 0.f;
                if (xok && r < R) {
                    int ci = r / (KSZ * KSZ); int rem = r - ci * (KSZ * KSZ);
                    int kh = rem / KSZ, kw = rem - kh * KSZ;
                    int hi = hi0 + kh, wi = wi0 + kw;
                    if ((unsigned)hi < (unsigned)Hin && (unsigned)wi < (unsigned)Win)
                        v = inb[((size_t)ci * Hin + hi) * Win + wi];
                }
                bv[q] = v;
            }
            #pragma unroll
            for (int qq = 0; qq < 4; ++qq) {
                short hh[4], ll[4];
                #pragma unroll
                for (int j = 0; j < 4; ++j) {
                    float x = bv[qq * 4 + j];
                    short h = f2bf_rne(x);
                    hh[j] = h;
                    ll[j] = f2bf_rne(x - bf2f(h));
                }
                int ln = bnl + 16 * qq;
                int a = bnt * 1024 + ln * 16 + beb * 2;
                a ^= (bnt & 7) << 4;
                *(short4*)((char*)Bh + a) = make_short4(hh[0], hh[1], hh[2], hh[3]);
                *(short4*)((char*)Bl + a) = make_short4(ll[0], ll[1], ll[2], ll[3]);
            }
        }
        __syncthreads();

        // ---- fragments + 3-term MFMA
        {
            bf16x8 fah[4], fal[4], fbh[4], fbl[4];
            #pragma unroll
            for (int mi = 0; mi < 4; ++mi) {
                int t = wr * 4 + mi;
                int off = t * 1024 + lane * 16; off ^= (t & 7) << 4;
                fah[mi] = *(const bf16x8*)((const char*)Ah + off);
                fal[mi] = *(const bf16x8*)((const char*)Al + off);
            }
            #pragma unroll
            for (int ni = 0; ni < 4; ++ni) {
                int t = wc * 4 + ni;
                int off = t * 1024 + lane * 16; off ^= (t & 7) << 4;
                fbh[ni] = *(const bf16x8*)((const char*)Bh + off);
                fbl[ni] = *(const bf16x8*)((const char*)Bl + off);
            }
            #pragma unroll
            for (int mi = 0; mi < 4; ++mi)
                #pragma unroll
                for (int ni = 0; ni < 4; ++ni) {
                    acc[mi][ni] = __builtin_amdgcn_mfma_f32_16x16x32_bf16(fah[mi], fbh[ni], acc[mi][ni], 0, 0, 0);
                    acc[mi][ni] = __builtin_amdgcn_mfma_f32_16x16x32_bf16(fah[mi], fbl[ni], acc[mi][ni], 0, 0, 0);
                    acc[mi][ni] = __builtin_amdgcn_mfma_f32_16x16x32_bf16(fal[mi], fbh[ni], acc[mi][ni], 0, 0, 0);
                }
        }
        __syncthreads();
    }

    // ---- epilogue: bias + scale + relu, NCHW scatter
    // C/D layout (verified): col = lane&15, row = (lane>>4)*4 + reg
    const int colc = lane & 15;
    const int rowb = (lane >> 4) * 4;
    #pragma unroll
    for (int ni = 0; ni < 4; ++ni) {
        int sp = sp0 + (wc * 4 + ni) * 16 + colc;
        if (sp >= NSP) continue;
        int n = sp / HW; int pp = sp - n * HW;
        #pragma unroll
        for (int mi = 0; mi < 4; ++mi) {
            #pragma unroll
            for (int j = 0; j < 4; ++j) {
                int cop = co0 + (wr * 4 + mi) * 16 + rowb + j;
                if (cop >= cog) continue;
                int co = g * cog + cop;
                float v = bs[co] + inscale * acc[mi][ni][j];
                out[((size_t)n * Cout + co) * HW + pp] = fmaxf(v, 0.f);
            }
        }
    }
}

// ============ split-K NT GEMM: part[kz] = A[M,krange] @ W[N,krange]^T =========
__global__ __launch_bounds__(256) void gemm64_nt_k(
    const float* __restrict__ A, const float* __restrict__ W,
    float* __restrict__ part, int M, int N, int K, int kchunk)
{
    const int tx = threadIdx.x, ty = threadIdx.y;
    const int tid = ty * 16 + tx;
    const int m0 = blockIdx.y * 64, n0 = blockIdx.x * 64;
    const int kz = blockIdx.z;
    const int kbeg = kz * kchunk;
    const int kend = min(K, kbeg + kchunk);
    __shared__ float As[16][68], Bs[16][68];
    float acc[4][4] = {};

    const int lr = tid >> 2;
    const int lk4 = (tid & 3) * 4;
    const bool arow_ok = (m0 + lr) < M;
    const bool wrow_ok = (n0 + lr) < N;
    const float* arow = A + (size_t)(m0 + lr) * K;
    const float* wrow = W + (size_t)(n0 + lr) * K;

    for (int k0 = kbeg; k0 < kend; k0 += 16) {
        if (arow_ok && (k0 + lk4 + 3) < kend) {
            float4 v = *(const float4*)(arow + k0 + lk4);
            As[lk4 + 0][lr] = v.x; As[lk4 + 1][lr] = v.y; As[lk4 + 2][lr] = v.z; As[lk4 + 3][lr] = v.w;
        } else {
            #pragma unroll
            for (int q = 0; q < 4; ++q) {
                int k = k0 + lk4 + q;
                As[lk4 + q][lr] = (arow_ok && k < kend) ? arow[k] : 0.f;
            }
        }
        if (wrow_ok && (k0 + lk4 + 3) < kend) {
            float4 v = *(const float4*)(wrow + k0 + lk4);
            Bs[lk4 + 0][lr] = v.x; Bs[lk4 + 1][lr] = v.y; Bs[lk4 + 2][lr] = v.z; Bs[lk4 + 3][lr] = v.w;
        } else {
            #pragma unroll
            for (int q = 0; q < 4; ++q) {
                int k = k0 + lk4 + q;
                Bs[lk4 + q][lr] = (wrow_ok && k < kend) ? wrow[k] : 0.f;
            }
        }
        __syncthreads();
        #pragma unroll
        for (int kk = 0; kk < 16; ++kk) {
            float a[4], b[4];
            *(float4*)a = *(const float4*)&As[kk][ty * 4];
            *(float4*)b = *(const float4*)&Bs[kk][tx * 4];
            #pragma unroll
            for (int i = 0; i < 4; ++i)
                #pragma unroll
                for (int j = 0; j < 4; ++j)
                    acc[i][j] = fmaf(a[i], b[j], acc[i][j]);
        }
        __syncthreads();
    }
    float* pout = part + (size_t)kz * M * N;
    #pragma unroll
    for (int i = 0; i < 4; ++i) {
        int row = m0 + ty * 4 + i;
        if (row >= M) continue;
        #pragma unroll
        for (int j = 0; j < 4; ++j) {
            int col = n0 + tx * 4 + j;
            if (col >= N) continue;
            pout[(size_t)row * N + col] = acc[i][j];
        }
    }
}

// ============ split-K NN GEMM: part[kz] = A[M,krange] @ W[krange,N] ===========
__global__ __launch_bounds__(256) void gemm64_nn_k(
    const float* __restrict__ A, const float* __restrict__ W,
    float* __restrict__ part, int M, int N, int K, int kchunk)
{
    const int tx = threadIdx.x, ty = threadIdx.y;
    const int tid = ty * 16 + tx;
    const int m0 = blockIdx.y * 64, n0 = blockIdx.x * 64;
    const int kz = blockIdx.z;
    const int kbeg = kz * kchunk;
    const int kend = min(K, kbeg + kchunk);
    __shared__ float As[16][68], Bs[16][68];
    float acc[4][4] = {};

    const int lr = tid >> 2;
    const int lk4 = (tid & 3) * 4;
    const bool arow_ok = (m0 + lr) < M;
    const float* arow = A + (size_t)(m0 + lr) * K;
    const int bkk = tid >> 4;
    const int bn4 = (tid & 15) * 4;

    for (int k0 = kbeg; k0 < kend; k0 += 16) {
        if (arow_ok && (k0 + lk4 + 3) < kend) {
            float4 v = *(const float4*)(arow + k0 + lk4);
            As[lk4 + 0][lr] = v.x; As[lk4 + 1][lr] = v.y; As[lk4 + 2][lr] = v.z; As[lk4 + 3][lr] = v.w;
        } else {
            #pragma unroll
            for (int q = 0; q < 4; ++q) {
                int k = k0 + lk4 + q;
                As[lk4 + q][lr] = (arow_ok && k < kend) ? arow[k] : 0.f;
            }
        }
        if ((k0 + bkk) < kend && (n0 + bn4 + 3) < N) {
            float4 v = *(const float4*)(W + (size_t)(k0 + bkk) * N + n0 + bn4);
            Bs[bkk][bn4 + 0] = v.x; Bs[bkk][bn4 + 1] = v.y; Bs[bkk][bn4 + 2] = v.z; Bs[bkk][bn4 + 3] = v.w;
        } else {
            #pragma unroll
            for (int q = 0; q < 4; ++q) {
                int col = n0 + bn4 + q;
                Bs[bkk][bn4 + q] = ((k0 + bkk) < kend && col < N) ? W[(size_t)(k0 + bkk) * N + col] : 0.f;
            }
        }
        __syncthreads();
        #pragma unroll
        for (int kk = 0; kk < 16; ++kk) {
            float a[4], b[4];
            *(float4*)a = *(const float4*)&As[kk][ty * 4];
            *(float4*)b = *(const float4*)&Bs[kk][tx * 4];
            #pragma unroll
            for (int i = 0; i < 4; ++i)
                #pragma unroll
                for (int j = 0; j < 4; ++j)
                    acc[i][j] = fmaf(a[i], b[j], acc[i][j]);
        }
        __syncthreads();
    }
    float* pout = part + (size_t)kz * M * N;
    #pragma unroll
    for (int i = 0; i < 4; ++i) {
        int row = m0 + ty * 4 + i;
        if (row >= M) continue;
        #pragma unroll
        for (int j = 0; j < 4; ++j) {
            int col = n0 + tx * 4 + j;
            if (col >= N) continue;
            pout[(size_t)row * N + col] = acc[i][j];
        }
    }
}

// ---------------- split-K reduce, fused bias + relu ----------------------------
__global__ void reduce_parts(const float* __restrict__ part, const float* __restrict__ bias,
                             float* __restrict__ out, int MN, int N, int P, int relu)
{
    int idx = blockIdx.x * blockDim.x + threadIdx.x;
    if (idx >= MN) return;
    float s = 0.f;
    for (int p = 0; p < P; ++p) s += part[(size_t)p * MN + idx];
    if (bias) s += bias[idx % N];
    out[idx] = relu ? fmaxf(s, 0.f) : s;
}

// ---------------- maxpool 3x3 stride 2 ----------------------------------------
__global__ void maxpool3s2_kernel(const float* __restrict__ in, float* __restrict__ out,
                                  int N, int C, int Hin, int Win, int Hout, int Wout)
{
    int idx = blockIdx.x * blockDim.x + threadIdx.x;
    int total = N * C * Hout * Wout;
    if (idx >= total) return;
    int wo = idx % Wout; int t = idx / Wout;
    int ho = t % Hout; t /= Hout;
    int c = t % C; int n = t / C;
    const float* ip = in + ((size_t)n * C + c) * Hin * Win;
    int h0 = ho * 2, w0 = wo * 2;
    float m = -1e30f;
    for (int dh = 0; dh < 3; ++dh)
        for (int dw = 0; dw < 3; ++dw)
            m = fmaxf(m, ip[(h0 + dh) * Win + (w0 + dw)]);
    out[idx] = m;
}

// ---------------- LRN (n=5, alpha=1e-4, beta=0.75, k=1) in-place --------------
__global__ void lrn_inplace_kernel(float* __restrict__ x, int N, int C, int HW)
{
    int idx = blockIdx.x * blockDim.x + threadIdx.x;
    int total = N * HW;
    if (idx >= total) return;
    int p = idx % HW; int n = idx / HW;
    float* base = x + (size_t)n * C * HW + p;
    const float an = 1e-4f / 5.f;
    float r0 = 0.f, r1 = 0.f, r2, r3, r4;
    r2 = base[0];
    r3 = (C > 1) ? base[(size_t)HW] : 0.f;
    r4 = (C > 2) ? base[(size_t)2 * HW] : 0.f;
    float s = r2 * r2 + r3 * r3 + r4 * r4;
    for (int c = 0; c < C; ++c) {
        base[(size_t)c * HW] = r2 / powf(1.f + an * s, 0.75f);
        s -= r0 * r0;
        r0 = r1; r1 = r2; r2 = r3; r3 = r4;
        r4 = (c + 3 < C) ? base[(size_t)(c + 3) * HW] : 0.f;
        s += r4 * r4;
    }
}

// ---------------- backward helpers --------------------------------------------
__global__ void g2m_kernel(const float* __restrict__ wc, const int* __restrict__ gt,
                           const float* __restrict__ h2, float* __restrict__ g2m,
                           int B, int D)
{
    int idx = blockIdx.x * blockDim.x + threadIdx.x;
    if (idx >= B * D) return;
    int b = idx / D, i = idx % D;
    g2m[idx] = (h2[idx] > 0.f) ? wc[(size_t)gt[b] * D + i] : 0.f;
}

__global__ void relumask_kernel(float* __restrict__ g, const float* __restrict__ h, int n)
{
    int idx = blockIdx.x * blockDim.x + threadIdx.x;
    if (idx >= n) return;
    if (h[idx] <= 0.f) g[idx] = 0.f;
}

__global__ void spatial_mean_kernel(const float* __restrict__ gf, float* __restrict__ sm,
                                    int B, int C, int HW)
{
    int idx = blockIdx.x * blockDim.x + threadIdx.x;
    if (idx >= B * HW) return;
    int b = idx / HW, p = idx % HW;
    const float* g = gf + (size_t)b * C * HW + p;
    float s = 0.f;
    for (int c = 0; c < C; ++c) s += g[(size_t)c * HW];
    sm[idx] = s / (float)C;
}

// ---------------- RSC spatial mask (exact JAX semantics) ----------------------
__global__ void rsc_mask_kernel(const float* __restrict__ sm, const float* __restrict__ u,
                                float* __restrict__ mask, int B, int HW, int drop)
{
    int b = blockIdx.x * blockDim.x + threadIdx.x;
    if (b >= B) return;
    const float* s = sm + (size_t)b * HW;
    const float* uu = u + (size_t)b * HW;
    float th = 0.f;
    for (int p = 0; p < HW; ++p) {
        float v = s[p];
        int cg = 0, ce = 0;
        for (int q = 0; q < HW; ++q) { cg += (s[q] > v); ce += (s[q] == v); }
        if (cg <= drop && drop < cg + ce) { th = v; break; }
    }
    float sc[36];
    bool chosen[36];
    for (int p = 0; p < HW; ++p) { sc[p] = (s[p] >= th) ? uu[p] : -1.0f; chosen[p] = false; }
    for (int r = 0; r < drop; ++r) {
        int best = 0; float bv = -1e30f;
        for (int p = 0; p < HW; ++p)
            if (!chosen[p] && sc[p] > bv) { bv = sc[p]; best = p; }
        chosen[best] = true;
    }
    float* m = mask + (size_t)b * HW;
    for (int p = 0; p < HW; ++p) m[p] = chosen[p] ? 0.f : 1.f;
}

__global__ void maskfeat_kernel(const float* __restrict__ feat, const float* __restrict__ mask,
                                float* __restrict__ featb, int B, int CHW, int HW)
{
    int idx = blockIdx.x * blockDim.x + threadIdx.x;
    if (idx >= B * CHW) return;
    int b = idx / CHW, j = idx % CHW;
    featb[idx] = feat[idx] * mask[(size_t)b * HW + (j % HW)];
}

__global__ void cv_kernel(const float* __restrict__ out0, const float* __restrict__ out1,
                          const int* __restrict__ gt, float* __restrict__ cv, int B, int NCc)
{
    int b = blockIdx.x * blockDim.x + threadIdx.x;
    if (b >= B) return;
    const float* a = out0 + (size_t)b * NCc;
    const float* c = out1 + (size_t)b * NCc;
    int g = gt[b];
    float m0 = -1e30f, m1 = -1e30f;
    for (int i = 0; i < NCc; ++i) { m0 = fmaxf(m0, a[i]); m1 = fmaxf(m1, c[i]); }
    float s0 = 0.f, s1 = 0.f;
    for (int i = 0; i < NCc; ++i) { s0 += expf(a[i] - m0); s1 += expf(c[i] - m1); }
    float pb = expf(a[g] - m0) / s0;
    float pa = expf(c[g] - m1) / s1;
    cv[b] = fmaxf(pb - pa - 1e-4f, 0.f);
}

__global__ void final_select_kernel(const float* __restrict__ cv, const float* __restrict__ out0,
                                    const float* __restrict__ out1, const int* __restrict__ flag,
                                    float* __restrict__ out, int B, int NCc, int kidx)
{
    __shared__ float thfg;
    int b = threadIdx.x;
    float v = cv[b];
    int cg = 0, ce = 0;
    for (int j = 0; j < B; ++j) { float w = cv[j]; cg += (w > v); ce += (w == v); }
    if (cg <= kidx && kidx < cg + ce) thfg = v;
    __syncthreads();
    bool keep = !(v > thfg);
    if (*flag == 0) keep = true;
    const float* src = keep ? out0 : out1;
    for (int c = 0; c < NCc; ++c)
        out[(size_t)b * NCc + c] = src[(size_t)b * NCc + c];
}

// ------------------------------------------------------------------------------
extern "C" void kernel_launch(void* const* d_in, const int* in_sizes, int n_in,
                              void* d_out, int out_size, void* d_ws, size_t ws_size,
                              hipStream_t stream) {
    const float* x   = (const float*)d_in[0];
    const int*   gt  = (const int*)d_in[1];
    const float* u   = (const float*)d_in[2];
    const int*   flag= (const int*)d_in[3];
    const float* w1  = (const float*)d_in[4];  const float* b1 = (const float*)d_in[5];
    const float* w2  = (const float*)d_in[6];  const float* b2 = (const float*)d_in[7];
    const float* w3  = (const float*)d_in[8];  const float* b3 = (const float*)d_in[9];
    const float* w4  = (const float*)d_in[10]; const float* b4 = (const float*)d_in[11];
    const float* w5  = (const float*)d_in[12]; const float* b5 = (const float*)d_in[13];
    const float* w6  = (const float*)d_in[14]; const float* b6 = (const float*)d_in[15];
    const float* w7  = (const float*)d_in[16]; const float* b7 = (const float*)d_in[17];
    const float* wc  = (const float*)d_in[18]; const float* bc = (const float*)d_in[19];
    float* out = (float*)d_out;
    (void)ws_size; (void)in_sizes; (void)n_in; (void)out_size;

    // ---- workspace layout (floats), peak ~153.5 MB with aliasing ----
    float* w = (float*)d_ws;
    float* p1 = w;                                   // 128*96*729   = 8,957,952
    float* p2 = p1 + (size_t)8957952;                // 128*256*169  = 5,537,792
    float* Br = p2 + (size_t)5537792;                // reused region, 23,887,872
    // phase 1: conv1 chunk buffer (32*96*3025 = 9,292,800)
    float* cbuf1 = Br;
    // phase 2: conv2 full output (128*256*729 = 23,887,872)
    float* cbuf2 = Br;
    // phase 3: everything after conv2 (sums to 23,332,992 < 23,887,872)
    float* c3    = Br;                               // 128*384*169 = 8,306,688
    float* c4    = c3 + (size_t)8306688;             // 8,306,688 (later: split-K partials)
    float* feat  = c4 + (size_t)8306688;             // 1,179,648
    float* featb = feat + (size_t)1179648;
    float* h1    = featb + (size_t)1179648;          // 524,288 each
    float* h2    = h1 + (size_t)524288;
    float* h1b   = h2 + (size_t)524288;
    float* h2b   = h1b + (size_t)524288;
    float* g1    = h2b + (size_t)524288;
    float* g2m   = g1 + (size_t)524288;
    float* gf    = g2m + (size_t)524288;             // 1,179,648
    float* out0  = gf + (size_t)1179648;             // 12,800
    float* out1  = out0 + 12800;
    float* sm    = out1 + 12800;                     // 4,608
    float* mask  = sm + 4608;
    float* cv    = mask + 4608;
    float* part  = c4;                               // split-K partials (c4 dead after conv5)

    // ---- layer 1: conv(3->96, k11 s4) + relu, pool 55->27, LRN (4 chunks of 32)
    for (int cs = 0; cs < 128; cs += 32) {
        conv_mfma128<11, 4, 0><<<dim3(CDIV(32 * 3025, 128), 1, 1), 256, 0, stream>>>(
            x + (size_t)cs * 3 * 227 * 227, w1, b1, cbuf1,
            32, 3, 227, 227, 96, 1, 55, 55, 57.6f);
        maxpool3s2_kernel<<<CDIV(32 * 96 * 729, 256), 256, 0, stream>>>(
            cbuf1, p1 + (size_t)cs * 96 * 729, 32, 96, 55, 55, 27, 27);
    }
    lrn_inplace_kernel<<<CDIV(128 * 729, 256), 256, 0, stream>>>(p1, 128, 96, 729);

    // ---- layer 2: conv(96->256, k5 p2 g2) full batch, pool 27->13, LRN ----
    conv_mfma128<5, 1, 2><<<dim3(CDIV(128 * 729, 128), 1, 2), 256, 0, stream>>>(
        p1, w2, b2, cbuf2, 128, 96, 27, 27, 256, 2, 27, 27, 1.f);
    maxpool3s2_kernel<<<CDIV(128 * 256 * 169, 256), 256, 0, stream>>>(
        cbuf2, p2, 128, 256, 27, 27, 13, 13);
    lrn_inplace_kernel<<<CDIV(128 * 169, 256), 256, 0, stream>>>(p2, 128, 256, 169);

    // ---- conv3 (256->384), conv4 (384->384 g2), conv5 (384->256 g2), pool ----
    conv_mfma128<3, 1, 1><<<dim3(CDIV(128 * 169, 128), 3, 1), 256, 0, stream>>>(
        p2, w3, b3, c3, 128, 256, 13, 13, 384, 1, 13, 13, 1.f);
    conv_mfma128<3, 1, 1><<<dim3(CDIV(128 * 169, 128), 2, 2), 256, 0, stream>>>(
        c3, w4, b4, c4, 128, 384, 13, 13, 384, 2, 13, 13, 1.f);
    conv_mfma128<3, 1, 1><<<dim3(CDIV(128 * 169, 128), 1, 2), 256, 0, stream>>>(
        c4, w5, b5, c3 /* reuse */, 128, 384, 13, 13, 256, 2, 13, 13, 1.f);
    maxpool3s2_kernel<<<CDIV(128 * 256 * 36, 256), 256, 0, stream>>>(
        c3, feat, 128, 256, 13, 13, 6, 6);

    // ---- head forward on feat (split-K GEMMs, partials in `part`) ----
    dim3 blk(16, 16);
    gemm64_nt_k<<<dim3(64, 2, 8), blk, 0, stream>>>(feat, w6, part, 128, 4096, 9216, 1152);
    reduce_parts<<<CDIV(128 * 4096, 256), 256, 0, stream>>>(part, b6, h1, 128 * 4096, 4096, 8, 1);
    gemm64_nt_k<<<dim3(64, 2, 8), blk, 0, stream>>>(h1, w7, part, 128, 4096, 4096, 512);
    reduce_parts<<<CDIV(128 * 4096, 256), 256, 0, stream>>>(part, b7, h2, 128 * 4096, 4096, 8, 1);
    gemm64_nt_k<<<dim3(2, 2, 8), blk, 0, stream>>>(h2, wc, part, 128, 100, 4096, 512);
    reduce_parts<<<CDIV(128 * 100, 256), 256, 0, stream>>>(part, bc, out0, 128 * 100, 100, 8, 0);

    // ---- analytic backward of sum(out[rows, gt]) w.r.t. feat ----
    g2m_kernel<<<CDIV(128 * 4096, 256), 256, 0, stream>>>(wc, gt, h2, g2m, 128, 4096);
    gemm64_nn_k<<<dim3(64, 2, 8), blk, 0, stream>>>(g2m, w7, part, 128, 4096, 4096, 512);
    reduce_parts<<<CDIV(128 * 4096, 256), 256, 0, stream>>>(part, nullptr, g1, 128 * 4096, 4096, 8, 0);
    relumask_kernel<<<CDIV(128 * 4096, 256), 256, 0, stream>>>(g1, h1, 128 * 4096);
    gemm64_nn_k<<<dim3(144, 2, 4), blk, 0, stream>>>(g1, w6, part, 128, 9216, 4096, 1024);
    reduce_parts<<<CDIV(128 * 9216, 256), 256, 0, stream>>>(part, nullptr, gf, 128 * 9216, 9216, 4, 0);

    // ---- RSC spatial mask ----
    spatial_mean_kernel<<<CDIV(128 * 36, 128), 128, 0, stream>>>(gf, sm, 128, 256, 36);
    rsc_mask_kernel<<<2, 64, 0, stream>>>(sm, u, mask, 128, 36, 12);

    // ---- masked head forward ----
    maskfeat_kernel<<<CDIV(128 * 9216, 256), 256, 0, stream>>>(feat, mask, featb, 128, 9216, 36);
    gemm64_nt_k<<<dim3(64, 2, 8), blk, 0, stream>>>(featb, w6, part, 128, 4096, 9216, 1152);
    reduce_parts<<<CDIV(128 * 4096, 256), 256, 0, stream>>>(part, b6, h1b, 128 * 4096, 4096, 8, 1);
    gemm64_nt_k<<<dim3(64, 2, 8), blk, 0, stream>>>(h1b, w7, part, 128, 4096, 4096, 512);
    reduce_parts<<<CDIV(128 * 4096, 256), 256, 0, stream>>>(part, b7, h2b, 128 * 4096, 4096, 8, 1);
    gemm64_nt_k<<<dim3(2, 2, 8), blk, 0, stream>>>(h2b, wc, part, 128, 100, 4096, 512);
    reduce_parts<<<CDIV(128 * 100, 256), 256, 0, stream>>>(part, bc, out1, 128 * 100, 100, 8, 0);

    // ---- cv, keep threshold (round(128/3)=43), final row select ----
    cv_kernel<<<1, 128, 0, stream>>>(out0, out1, gt, cv, 128, 100);
    final_select_kernel<<<1, 128, 0, stream>>>(cv, out0, out1, flag, out, 128, 100, 43);
}

// Round 2
// 2792.413 us; speedup vs baseline: 2.0347x; 1.1706x over previous
//
#include <hip/hip_runtime.h>

#define CDIV(a,b) (((a)+(b)-1)/(b))

typedef __attribute__((ext_vector_type(8))) short bf16x8;
typedef __attribute__((ext_vector_type(4))) float f32x4;

// pack fp32 -> {hi bf16 [31:16], lo bf16 [15:0]}, both RNE
__device__ __forceinline__ unsigned packsplit(float x) {
    union { float f; unsigned u; } a; a.f = x;
    unsigned r = a.u + 0x7fffu + ((a.u >> 16) & 1u);
    unsigned hi = r & 0xffff0000u;
    union { float f; unsigned u; } b; b.u = hi;
    float res = x - b.f;
    union { float f; unsigned u; } c; c.f = res;
    unsigned r2 = c.u + 0x7fffu + ((c.u >> 16) & 1u);
    return hi | (r2 >> 16);
}
__device__ __forceinline__ unsigned hipair(unsigned a, unsigned b){ return (a>>16)|(b&0xffff0000u); }
__device__ __forceinline__ unsigned lopair(unsigned a, unsigned b){ return (a&0xffffu)|(b<<16); }

// ---------------- elementwise fp32 -> packed split (with scale) ---------------
__global__ void pack_scale_kernel(const float* __restrict__ src, unsigned* __restrict__ dst,
                                  int n4, float scale)
{
    int i = blockIdx.x * blockDim.x + threadIdx.x;
    if (i >= n4) return;
    float4 v = ((const float4*)src)[i];
    uint4 o;
    o.x = packsplit(v.x * scale); o.y = packsplit(v.y * scale);
    o.z = packsplit(v.z * scale); o.w = packsplit(v.w * scale);
    ((uint4*)dst)[i] = o;
}

// ---------------- weight prepass: fp32 [G][cog][R] -> fragment-major slabs ---
// slab (g,cb,kt): 8192 shorts = [Ah 4096][Al 4096]; Ah[t*512 + ln*8 + e]
// (t=m-tile 0..7, ln=lane 0..63, e: k = kt*32 + (e<4 ? (ln>>4)*4+e : 16+(ln>>4)*4+e-4))
__global__ void wsplit_frag(const float* __restrict__ w, short* __restrict__ dst,
                            int G, int cog, int R, int CB, int niter)
{
    int idx = blockIdx.x * blockDim.x + threadIdx.x;
    int total = G * CB * niter * 512;
    if (idx >= total) return;
    int ln = idx & 63;
    int t  = (idx >> 6) & 7;
    int s  = idx >> 9;
    int kt = s % niter;
    int s2 = s / niter;
    int cb = s2 % CB;
    int g  = s2 / CB;
    int row = cb * 128 + t * 16 + (ln & 15);
    int qq = ln >> 4;
    bool rok = row < cog;
    const float* wr = w + (size_t)(g * cog + (rok ? row : 0)) * R;
    short hv[8], lv[8];
    #pragma unroll
    for (int e = 0; e < 8; ++e) {
        int k = kt * 32 + ((e < 4) ? (qq * 4 + e) : (16 + qq * 4 + e - 4));
        float x = (rok && k < R) ? wr[k] : 0.f;
        unsigned p = packsplit(x);
        hv[e] = (short)(p >> 16);
        lv[e] = (short)(p & 0xffffu);
    }
    short* sb = dst + (size_t)s * 8192 + t * 512 + ln * 8;
    *(short4*)(sb)     = make_short4(hv[0], hv[1], hv[2], hv[3]);
    *(short4*)(sb + 4) = make_short4(hv[4], hv[5], hv[6], hv[7]);
    short* sl = sb + 4096;
    *(short4*)(sl)     = make_short4(lv[0], lv[1], lv[2], lv[3]);
    *(short4*)(sl + 4) = make_short4(lv[4], lv[5], lv[6], lv[7]);
}

// ============ MFMA implicit-GEMM conv, packed-split inputs & weights =========
// in: packed u32 NCHW; wtr: fragment-major weight slabs; out fp32 or packed u32
template<int KSZ, int STRIDE, int PAD, int OUTPACK>
__global__ __launch_bounds__(256, 2) void conv_mfma128(
    const unsigned* __restrict__ in, const short* __restrict__ wtr,
    const float* __restrict__ bs, void* __restrict__ outv,
    int N, int Cin, int Hin, int Win, int Cout, int groups,
    int Hout, int Wout, int CB, int niter)
{
    const int cig = Cin / groups, cog = Cout / groups;
    const int R = cig * KSZ * KSZ;
    const int HW = Hout * Wout;
    const int NSP = N * HW;
    const int g = blockIdx.z;
    const int cb = blockIdx.y;
    const int sp0 = blockIdx.x * 128;
    const int co0 = cb * 128;
    const int tid = threadIdx.x;
    const int lane = tid & 63;
    const int wid = tid >> 6;
    const int wr = wid >> 1, wc = wid & 1;

    __shared__ __align__(16) short Ah[4096];
    __shared__ __align__(16) short Al[4096];
    __shared__ __align__(16) short Bh[4096];
    __shared__ __align__(16) short Bl[4096];

    f32x4 acc[4][4];
    #pragma unroll
    for (int i = 0; i < 4; ++i)
        #pragma unroll
        for (int j = 0; j < 4; ++j)
            acc[i][j] = (f32x4){0.f, 0.f, 0.f, 0.f};

    // B mapping: thread -> spatial s_ (0..127), qpair (0..1) covering qq=2qp,2qp+1
    const int s_ = tid & 127;
    const int qpair = tid >> 7;
    const int spx = sp0 + s_;
    const bool xok = spx < NSP;
    int xn = 0, xho = 0, xwo = 0;
    if (xok) { xn = spx / HW; int pp = spx - xn * HW; xho = pp / Wout; xwo = pp - xho * Wout; }
    const unsigned* inb = in + ((size_t)xn * Cin + (size_t)g * cig) * Hin * Win;
    const int hi0 = xho * STRIDE - PAD, wi0 = xwo * STRIDE - PAD;
    const int bnt = s_ >> 4, bnl = s_ & 15;
    const int lnE = bnl + 32 * qpair;   // slot for qq = 2*qpair
    const int lnO = lnE + 16;           // slot for qq = 2*qpair+1

    const short* slab0 = wtr + (size_t)((g * CB + cb) * niter) * 8192;

    for (int it = 0; it < niter; ++it) {
        const int r0 = it * 32;
        // ---- A: straight 16KB slab copy (already fragment-major hi/lo)
        {
            const uint4* src = (const uint4*)(slab0 + (size_t)it * 8192);
            uint4 a0 = src[tid], a1 = src[tid + 256];
            uint4 c0 = src[tid + 512], c1 = src[tid + 768];
            ((uint4*)Ah)[tid] = a0; ((uint4*)Ah)[tid + 256] = a1;
            ((uint4*)Al)[tid] = c0; ((uint4*)Al)[tid + 256] = c1;
        }
        // ---- B: im2col gather of two 8-k runs (k and k+16), packed u32 input
        {
            const int kA = r0 + qpair * 8;
            int ciA, khA, kwA, ciB, khB, kwB;
            { int kk = kA;      ciA = kk / (KSZ*KSZ); int rem = kk - ciA*(KSZ*KSZ); khA = rem / KSZ; kwA = rem - khA*KSZ; }
            { int kk = kA + 16; ciB = kk / (KSZ*KSZ); int rem = kk - ciB*(KSZ*KSZ); khB = rem / KSZ; kwB = rem - khB*KSZ; }
            unsigned uA[8], uB[8];
            #pragma unroll
            for (int e = 0; e < 8; ++e) {
                {
                    int hh = hi0 + khA, ww = wi0 + kwA;
                    unsigned v = 0u;
                    if (xok && (kA + e) < R && (unsigned)hh < (unsigned)Hin && (unsigned)ww < (unsigned)Win)
                        v = inb[(size_t)(ciA * Hin + hh) * Win + ww];
                    uA[e] = v;
                    if (++kwA == KSZ) { kwA = 0; if (++khA == KSZ) { khA = 0; ++ciA; } }
                }
                {
                    int hh = hi0 + khB, ww = wi0 + kwB;
                    unsigned v = 0u;
                    if (xok && (kA + 16 + e) < R && (unsigned)hh < (unsigned)Hin && (unsigned)ww < (unsigned)Win)
                        v = inb[(size_t)(ciB * Hin + hh) * Win + ww];
                    uB[e] = v;
                    if (++kwB == KSZ) { kwB = 0; if (++khB == KSZ) { khB = 0; ++ciB; } }
                }
            }
            uint4 d;
            d.x = hipair(uA[0], uA[1]); d.y = hipair(uA[2], uA[3]);
            d.z = hipair(uB[0], uB[1]); d.w = hipair(uB[2], uB[3]);
            ((uint4*)Bh)[bnt * 64 + lnE] = d;
            d.x = hipair(uA[4], uA[5]); d.y = hipair(uA[6], uA[7]);
            d.z = hipair(uB[4], uB[5]); d.w = hipair(uB[6], uB[7]);
            ((uint4*)Bh)[bnt * 64 + lnO] = d;
            d.x = lopair(uA[0], uA[1]); d.y = lopair(uA[2], uA[3]);
            d.z = lopair(uB[0], uB[1]); d.w = lopair(uB[2], uB[3]);
            ((uint4*)Bl)[bnt * 64 + lnE] = d;
            d.x = lopair(uA[4], uA[5]); d.y = lopair(uA[6], uA[7]);
            d.z = lopair(uB[4], uB[5]); d.w = lopair(uB[6], uB[7]);
            ((uint4*)Bl)[bnt * 64 + lnO] = d;
        }
        __syncthreads();
        // ---- 3-term MFMA
        {
            bf16x8 fah[4], fal[4], fbh[4], fbl[4];
            #pragma unroll
            for (int mi = 0; mi < 4; ++mi) {
                int off = (wr * 4 + mi) * 512 + lane * 8;
                fah[mi] = *(const bf16x8*)(Ah + off);
                fal[mi] = *(const bf16x8*)(Al + off);
            }
            #pragma unroll
            for (int ni = 0; ni < 4; ++ni) {
                int off = (wc * 4 + ni) * 512 + lane * 8;
                fbh[ni] = *(const bf16x8*)(Bh + off);
                fbl[ni] = *(const bf16x8*)(Bl + off);
            }
            #pragma unroll
            for (int mi = 0; mi < 4; ++mi)
                #pragma unroll
                for (int ni = 0; ni < 4; ++ni) {
                    acc[mi][ni] = __builtin_amdgcn_mfma_f32_16x16x32_bf16(fah[mi], fbh[ni], acc[mi][ni], 0, 0, 0);
                    acc[mi][ni] = __builtin_amdgcn_mfma_f32_16x16x32_bf16(fah[mi], fbl[ni], acc[mi][ni], 0, 0, 0);
                    acc[mi][ni] = __builtin_amdgcn_mfma_f32_16x16x32_bf16(fal[mi], fbh[ni], acc[mi][ni], 0, 0, 0);
                }
        }
        __syncthreads();
    }

    // ---- epilogue: bias + relu, NCHW scatter (fp32 or packed u32)
    const int colc = lane & 15;
    const int rowb = (lane >> 4) * 4;
    #pragma unroll
    for (int ni = 0; ni < 4; ++ni) {
        int sp = sp0 + (wc * 4 + ni) * 16 + colc;
        if (sp >= NSP) continue;
        int n = sp / HW; int pp = sp - n * HW;
        #pragma unroll
        for (int mi = 0; mi < 4; ++mi) {
            #pragma unroll
            for (int j = 0; j < 4; ++j) {
                int cop = co0 + (wr * 4 + mi) * 16 + rowb + j;
                if (cop >= cog) continue;
                int co = g * cog + cop;
                float v = fmaxf(bs[co] + acc[mi][ni][j], 0.f);
                size_t oi = ((size_t)n * Cout + co) * HW + pp;
                if (OUTPACK) ((unsigned*)outv)[oi] = packsplit(v);
                else         ((float*)outv)[oi] = v;
            }
        }
    }
}

// ============ split-K NT GEMM: part[kz] = A[M,krange] @ W[N,krange]^T =========
__global__ __launch_bounds__(256) void gemm64_nt_k(
    const float* __restrict__ A, const float* __restrict__ W,
    float* __restrict__ part, int M, int N, int K, int kchunk)
{
    const int tx = threadIdx.x, ty = threadIdx.y;
    const int tid = ty * 16 + tx;
    const int m0 = blockIdx.y * 64, n0 = blockIdx.x * 64;
    const int kz = blockIdx.z;
    const int kbeg = kz * kchunk;
    const int kend = min(K, kbeg + kchunk);
    __shared__ float As[16][68], Bs[16][68];
    float acc[4][4] = {};

    const int lr = tid >> 2;
    const int lk4 = (tid & 3) * 4;
    const bool arow_ok = (m0 + lr) < M;
    const bool wrow_ok = (n0 + lr) < N;
    const float* arow = A + (size_t)(m0 + lr) * K;
    const float* wrow = W + (size_t)(n0 + lr) * K;

    for (int k0 = kbeg; k0 < kend; k0 += 16) {
        if (arow_ok && (k0 + lk4 + 3) < kend) {
            float4 v = *(const float4*)(arow + k0 + lk4);
            As[lk4 + 0][lr] = v.x; As[lk4 + 1][lr] = v.y; As[lk4 + 2][lr] = v.z; As[lk4 + 3][lr] = v.w;
        } else {
            #pragma unroll
            for (int q = 0; q < 4; ++q) {
                int k = k0 + lk4 + q;
                As[lk4 + q][lr] = (arow_ok && k < kend) ? arow[k] : 0.f;
            }
        }
        if (wrow_ok && (k0 + lk4 + 3) < kend) {
            float4 v = *(const float4*)(wrow + k0 + lk4);
            Bs[lk4 + 0][lr] = v.x; Bs[lk4 + 1][lr] = v.y; Bs[lk4 + 2][lr] = v.z; Bs[lk4 + 3][lr] = v.w;
        } else {
            #pragma unroll
            for (int q = 0; q < 4; ++q) {
                int k = k0 + lk4 + q;
                Bs[lk4 + q][lr] = (wrow_ok && k < kend) ? wrow[k] : 0.f;
            }
        }
        __syncthreads();
        #pragma unroll
        for (int kk = 0; kk < 16; ++kk) {
            float a[4], b[4];
            *(float4*)a = *(const float4*)&As[kk][ty * 4];
            *(float4*)b = *(const float4*)&Bs[kk][tx * 4];
            #pragma unroll
            for (int i = 0; i < 4; ++i)
                #pragma unroll
                for (int j = 0; j < 4; ++j)
                    acc[i][j] = fmaf(a[i], b[j], acc[i][j]);
        }
        __syncthreads();
    }
    float* pout = part + (size_t)kz * M * N;
    #pragma unroll
    for (int i = 0; i < 4; ++i) {
        int row = m0 + ty * 4 + i;
        if (row >= M) continue;
        #pragma unroll
        for (int j = 0; j < 4; ++j) {
            int col = n0 + tx * 4 + j;
            if (col >= N) continue;
            pout[(size_t)row * N + col] = acc[i][j];
        }
    }
}

// ============ split-K NN GEMM: part[kz] = A[M,krange] @ W[krange,N] ===========
__global__ __launch_bounds__(256) void gemm64_nn_k(
    const float* __restrict__ A, const float* __restrict__ W,
    float* __restrict__ part, int M, int N, int K, int kchunk)
{
    const int tx = threadIdx.x, ty = threadIdx.y;
    const int tid = ty * 16 + tx;
    const int m0 = blockIdx.y * 64, n0 = blockIdx.x * 64;
    const int kz = blockIdx.z;
    const int kbeg = kz * kchunk;
    const int kend = min(K, kbeg + kchunk);
    __shared__ float As[16][68], Bs[16][68];
    float acc[4][4] = {};

    const int lr = tid >> 2;
    const int lk4 = (tid & 3) * 4;
    const bool arow_ok = (m0 + lr) < M;
    const float* arow = A + (size_t)(m0 + lr) * K;
    const int bkk = tid >> 4;
    const int bn4 = (tid & 15) * 4;

    for (int k0 = kbeg; k0 < kend; k0 += 16) {
        if (arow_ok && (k0 + lk4 + 3) < kend) {
            float4 v = *(const float4*)(arow + k0 + lk4);
            As[lk4 + 0][lr] = v.x; As[lk4 + 1][lr] = v.y; As[lk4 + 2][lr] = v.z; As[lk4 + 3][lr] = v.w;
        } else {
            #pragma unroll
            for (int q = 0; q < 4; ++q) {
                int k = k0 + lk4 + q;
                As[lk4 + q][lr] = (arow_ok && k < kend) ? arow[k] : 0.f;
            }
        }
        if ((k0 + bkk) < kend && (n0 + bn4 + 3) < N) {
            float4 v = *(const float4*)(W + (size_t)(k0 + bkk) * N + n0 + bn4);
            Bs[bkk][bn4 + 0] = v.x; Bs[bkk][bn4 + 1] = v.y; Bs[bkk][bn4 + 2] = v.z; Bs[bkk][bn4 + 3] = v.w;
        } else {
            #pragma unroll
            for (int q = 0; q < 4; ++q) {
                int col = n0 + bn4 + q;
                Bs[bkk][bn4 + q] = ((k0 + bkk) < kend && col < N) ? W[(size_t)(k0 + bkk) * N + col] : 0.f;
            }
        }
        __syncthreads();
        #pragma unroll
        for (int kk = 0; kk < 16; ++kk) {
            float a[4], b[4];
            *(float4*)a = *(const float4*)&As[kk][ty * 4];
            *(float4*)b = *(const float4*)&Bs[kk][tx * 4];
            #pragma unroll
            for (int i = 0; i < 4; ++i)
                #pragma unroll
                for (int j = 0; j < 4; ++j)
                    acc[i][j] = fmaf(a[i], b[j], acc[i][j]);
        }
        __syncthreads();
    }
    float* pout = part + (size_t)kz * M * N;
    #pragma unroll
    for (int i = 0; i < 4; ++i) {
        int row = m0 + ty * 4 + i;
        if (row >= M) continue;
        #pragma unroll
        for (int j = 0; j < 4; ++j) {
            int col = n0 + tx * 4 + j;
            if (col >= N) continue;
            pout[(size_t)row * N + col] = acc[i][j];
        }
    }
}

// ---------------- split-K reduce, fused bias + relu ----------------------------
__global__ void reduce_parts(const float* __restrict__ part, const float* __restrict__ bias,
                             float* __restrict__ out, int MN, int N, int P, int relu)
{
    int idx = blockIdx.x * blockDim.x + threadIdx.x;
    if (idx >= MN) return;
    float s = 0.f;
    for (int p = 0; p < P; ++p) s += part[(size_t)p * MN + idx];
    if (bias) s += bias[idx % N];
    out[idx] = relu ? fmaxf(s, 0.f) : s;
}

// ---------------- maxpool 3x3 stride 2 ----------------------------------------
__global__ void maxpool3s2_kernel(const float* __restrict__ in, float* __restrict__ out,
                                  int N, int C, int Hin, int Win, int Hout, int Wout)
{
    int idx = blockIdx.x * blockDim.x + threadIdx.x;
    int total = N * C * Hout * Wout;
    if (idx >= total) return;
    int wo = idx % Wout; int t = idx / Wout;
    int ho = t % Hout; t /= Hout;
    int c = t % C; int n = t / C;
    const float* ip = in + ((size_t)n * C + c) * Hin * Win;
    int h0 = ho * 2, w0 = wo * 2;
    float m = -1e30f;
    for (int dh = 0; dh < 3; ++dh)
        for (int dw = 0; dw < 3; ++dw)
            m = fmaxf(m, ip[(h0 + dh) * Win + (w0 + dw)]);
    out[idx] = m;
}

// ------- LRN (n=5) in-place, output written as packed {hi,lo} u32 -------------
__global__ void lrn_pack_kernel(float* __restrict__ x, int N, int C, int HW)
{
    int idx = blockIdx.x * blockDim.x + threadIdx.x;
    int total = N * HW;
    if (idx >= total) return;
    int p = idx % HW; int n = idx / HW;
    float* base = x + (size_t)n * C * HW + p;
    unsigned* ubase = (unsigned*)base;
    const float an = 1e-4f / 5.f;
    float r0 = 0.f, r1 = 0.f, r2, r3, r4;
    r2 = base[0];
    r3 = (C > 1) ? base[(size_t)HW] : 0.f;
    r4 = (C > 2) ? base[(size_t)2 * HW] : 0.f;
    float s = r2 * r2 + r3 * r3 + r4 * r4;
    for (int c = 0; c < C; ++c) {
        float y = r2 / powf(1.f + an * s, 0.75f);
        ubase[(size_t)c * HW] = packsplit(y);
        s -= r0 * r0;
        r0 = r1; r1 = r2; r2 = r3; r3 = r4;
        r4 = (c + 3 < C) ? base[(size_t)(c + 3) * HW] : 0.f;
        s += r4 * r4;
    }
}

// ---------------- backward helpers --------------------------------------------
__global__ void g2m_kernel(const float* __restrict__ wc, const int* __restrict__ gt,
                           const float* __restrict__ h2, float* __restrict__ g2m,
                           int B, int D)
{
    int idx = blockIdx.x * blockDim.x + threadIdx.x;
    if (idx >= B * D) return;
    int b = idx / D, i = idx % D;
    g2m[idx] = (h2[idx] > 0.f) ? wc[(size_t)gt[b] * D + i] : 0.f;
}

__global__ void relumask_kernel(float* __restrict__ g, const float* __restrict__ h, int n)
{
    int idx = blockIdx.x * blockDim.x + threadIdx.x;
    if (idx >= n) return;
    if (h[idx] <= 0.f) g[idx] = 0.f;
}

__global__ void spatial_mean_kernel(const float* __restrict__ gf, float* __restrict__ sm,
                                    int B, int C, int HW)
{
    int idx = blockIdx.x * blockDim.x + threadIdx.x;
    if (idx >= B * HW) return;
    int b = idx / HW, p = idx % HW;
    const float* g = gf + (size_t)b * C * HW + p;
    float s = 0.f;
    for (int c = 0; c < C; ++c) s += g[(size_t)c * HW];
    sm[idx] = s / (float)C;
}

// ---------------- RSC spatial mask (exact JAX semantics) ----------------------
__global__ void rsc_mask_kernel(const float* __restrict__ sm, const float* __restrict__ u,
                                float* __restrict__ mask, int B, int HW, int drop)
{
    int b = blockIdx.x * blockDim.x + threadIdx.x;
    if (b >= B) return;
    const float* s = sm + (size_t)b * HW;
    const float* uu = u + (size_t)b * HW;
    float th = 0.f;
    for (int p = 0; p < HW; ++p) {
        float v = s[p];
        int cg = 0, ce = 0;
        for (int q = 0; q < HW; ++q) { cg += (s[q] > v); ce += (s[q] == v); }
        if (cg <= drop && drop < cg + ce) { th = v; break; }
    }
    float sc[36];
    bool chosen[36];
    for (int p = 0; p < HW; ++p) { sc[p] = (s[p] >= th) ? uu[p] : -1.0f; chosen[p] = false; }
    for (int r = 0; r < drop; ++r) {
        int best = 0; float bv = -1e30f;
        for (int p = 0; p < HW; ++p)
            if (!chosen[p] && sc[p] > bv) { bv = sc[p]; best = p; }
        chosen[best] = true;
    }
    float* m = mask + (size_t)b * HW;
    for (int p = 0; p < HW; ++p) m[p] = chosen[p] ? 0.f : 1.f;
}

__global__ void maskfeat_kernel(const float* __restrict__ feat, const float* __restrict__ mask,
                                float* __restrict__ featb, int B, int CHW, int HW)
{
    int idx = blockIdx.x * blockDim.x + threadIdx.x;
    if (idx >= B * CHW) return;
    int b = idx / CHW, j = idx % CHW;
    featb[idx] = feat[idx] * mask[(size_t)b * HW + (j % HW)];
}

__global__ void cv_kernel(const float* __restrict__ out0, const float* __restrict__ out1,
                          const int* __restrict__ gt, float* __restrict__ cv, int B, int NCc)
{
    int b = blockIdx.x * blockDim.x + threadIdx.x;
    if (b >= B) return;
    const float* a = out0 + (size_t)b * NCc;
    const float* c = out1 + (size_t)b * NCc;
    int g = gt[b];
    float m0 = -1e30f, m1 = -1e30f;
    for (int i = 0; i < NCc; ++i) { m0 = fmaxf(m0, a[i]); m1 = fmaxf(m1, c[i]); }
    float s0 = 0.f, s1 = 0.f;
    for (int i = 0; i < NCc; ++i) { s0 += expf(a[i] - m0); s1 += expf(c[i] - m1); }
    float pb = expf(a[g] - m0) / s0;
    float pa = expf(c[g] - m1) / s1;
    cv[b] = fmaxf(pb - pa - 1e-4f, 0.f);
}

__global__ void final_select_kernel(const float* __restrict__ cv, const float* __restrict__ out0,
                                    const float* __restrict__ out1, const int* __restrict__ flag,
                                    float* __restrict__ out, int B, int NCc, int kidx)
{
    __shared__ float thfg;
    int b = threadIdx.x;
    float v = cv[b];
    int cg = 0, ce = 0;
    for (int j = 0; j < B; ++j) { float w = cv[j]; cg += (w > v); ce += (w == v); }
    if (cg <= kidx && kidx < cg + ce) thfg = v;
    __syncthreads();
    bool keep = !(v > thfg);
    if (*flag == 0) keep = true;
    const float* src = keep ? out0 : out1;
    for (int c = 0; c < NCc; ++c)
        out[(size_t)b * NCc + c] = src[(size_t)b * NCc + c];
}

// ------------------------------------------------------------------------------
extern "C" void kernel_launch(void* const* d_in, const int* in_sizes, int n_in,
                              void* d_out, int out_size, void* d_ws, size_t ws_size,
                              hipStream_t stream) {
    const float* x   = (const float*)d_in[0];
    const int*   gt  = (const int*)d_in[1];
    const float* u   = (const float*)d_in[2];
    const int*   flag= (const int*)d_in[3];
    const float* w1  = (const float*)d_in[4];  const float* b1 = (const float*)d_in[5];
    const float* w2  = (const float*)d_in[6];  const float* b2 = (const float*)d_in[7];
    const float* w3  = (const float*)d_in[8];  const float* b3 = (const float*)d_in[9];
    const float* w4  = (const float*)d_in[10]; const float* b4 = (const float*)d_in[11];
    const float* w5  = (const float*)d_in[12]; const float* b5 = (const float*)d_in[13];
    const float* w6  = (const float*)d_in[14]; const float* b6 = (const float*)d_in[15];
    const float* w7  = (const float*)d_in[16]; const float* b7 = (const float*)d_in[17];
    const float* wc  = (const float*)d_in[18]; const float* bc = (const float*)d_in[19];
    float* out = (float*)d_out;
    (void)ws_size; (void)in_sizes; (void)n_in; (void)out_size;

    // ---- workspace layout (4B units), total 40,955,904 floats ≈ 163.8 MB ----
    float* w = (float*)d_ws;
    float* p1   = w;                                 // 8,957,952 (fp32 -> packed in place)
    float* p2   = p1 + (size_t)8957952;              // 5,537,792 (fp32 -> packed in place)
    float* wtrF = p2 + (size_t)5537792;              // 2,572,288 (= 5,144,576 shorts)
    float* Br   = wtrF + (size_t)2572288;            // 23,887,872 reused region
    short* wtrS = (short*)wtrF;

    // phase 1: cbuf1 = Br[0, 9,292,800); xs = Br + 9,292,800 (4,946,784 u32)
    float*    cbuf1 = Br;
    unsigned* xs    = (unsigned*)(Br + (size_t)9292800);
    // phase 2: cbuf2 = Br (23,887,872 fp32)
    float* cbuf2 = Br;
    // phase 3 (inside Br, sums to 23,332,992):
    unsigned* c3s  = (unsigned*)Br;                  // 8,306,688 (packed conv3 out)
    unsigned* c4s  = (unsigned*)(Br + (size_t)8306688); // 8,306,688 (packed conv4 out)
    float* c5out   = Br;                             // 5,537,792 fp32 (over dead c3s)
    float* part    = Br + (size_t)8306688;           // split-K partials (over dead c4s)
    float* feat    = Br + (size_t)16613376;          // 1,179,648
    float* featb   = feat + (size_t)1179648;
    float* h1      = featb + (size_t)1179648;        // 524,288 each
    float* h2      = h1 + (size_t)524288;
    float* h1b     = h2 + (size_t)524288;
    float* h2b     = h1b + (size_t)524288;
    float* g1      = h2b + (size_t)524288;
    float* g2m     = g1 + (size_t)524288;
    float* gf      = g2m + (size_t)524288;           // 1,179,648
    float* out0    = gf + (size_t)1179648;           // 12,800
    float* out1    = out0 + 12800;
    float* sm      = out1 + 12800;                   // 4,608
    float* mask    = sm + 4608;
    float* cv      = mask + 4608;

    // wtr slab offsets (shorts): per conv G*CB*niter*8192
    const size_t o1 = 0;          // conv1: 1*1*12  -> 98,304
    const size_t o2 = 98304;      // conv2: 2*1*38  -> 622,592
    const size_t o3 = 720896;     // conv3: 1*3*72  -> 1,769,472
    const size_t o4 = 2490368;    // conv4: 2*2*54  -> 1,769,472
    const size_t o5 = 4259840;    // conv5: 2*1*54  -> 884,736 (end 5,144,576)

    // ---- weight prepass (fragment-major packed-split slabs) ----
    wsplit_frag<<<CDIV(1*1*12*512, 256), 256, 0, stream>>>(w1, wtrS + o1, 1,  96,  363, 1, 12);
    wsplit_frag<<<CDIV(2*1*38*512, 256), 256, 0, stream>>>(w2, wtrS + o2, 2, 128, 1200, 1, 38);
    wsplit_frag<<<CDIV(1*3*72*512, 256), 256, 0, stream>>>(w3, wtrS + o3, 1, 384, 2304, 3, 72);
    wsplit_frag<<<CDIV(2*2*54*512, 256), 256, 0, stream>>>(w4, wtrS + o4, 2, 192, 1728, 2, 54);
    wsplit_frag<<<CDIV(2*1*54*512, 256), 256, 0, stream>>>(w5, wtrS + o5, 2, 128, 1728, 1, 54);

    // ---- layer 1: pack(57.6*x) chunk, conv(3->96, k11 s4), pool 55->27, LRN ----
    for (int cs = 0; cs < 128; cs += 32) {
        pack_scale_kernel<<<CDIV(1236696, 256), 256, 0, stream>>>(
            x + (size_t)cs * 154587, xs, 1236696, 57.6f);
        conv_mfma128<11, 4, 0, 0><<<dim3(757, 1, 1), 256, 0, stream>>>(
            xs, wtrS + o1, b1, cbuf1, 32, 3, 227, 227, 96, 1, 55, 55, 1, 12);
        maxpool3s2_kernel<<<CDIV(32 * 96 * 729, 256), 256, 0, stream>>>(
            cbuf1, p1 + (size_t)cs * 96 * 729, 32, 96, 55, 55, 27, 27);
    }
    lrn_pack_kernel<<<CDIV(128 * 729, 256), 256, 0, stream>>>(p1, 128, 96, 729);

    // ---- layer 2: conv(96->256, k5 p2 g2), pool 27->13, LRN ----
    conv_mfma128<5, 1, 2, 0><<<dim3(729, 1, 2), 256, 0, stream>>>(
        (const unsigned*)p1, wtrS + o2, b2, cbuf2, 128, 96, 27, 27, 256, 2, 27, 27, 1, 38);
    maxpool3s2_kernel<<<CDIV(128 * 256 * 169, 256), 256, 0, stream>>>(
        cbuf2, p2, 128, 256, 27, 27, 13, 13);
    lrn_pack_kernel<<<CDIV(128 * 169, 256), 256, 0, stream>>>(p2, 128, 256, 169);

    // ---- conv3 (256->384, packed out), conv4 (384->384 g2, packed out),
    //      conv5 (384->256 g2, fp32 out), pool 13->6 ----
    conv_mfma128<3, 1, 1, 1><<<dim3(169, 3, 1), 256, 0, stream>>>(
        (const unsigned*)p2, wtrS + o3, b3, c3s, 128, 256, 13, 13, 384, 1, 13, 13, 3, 72);
    conv_mfma128<3, 1, 1, 1><<<dim3(169, 2, 2), 256, 0, stream>>>(
        c3s, wtrS + o4, b4, c4s, 128, 384, 13, 13, 384, 2, 13, 13, 2, 54);
    conv_mfma128<3, 1, 1, 0><<<dim3(169, 1, 2), 256, 0, stream>>>(
        c4s, wtrS + o5, b5, c5out, 128, 384, 13, 13, 256, 2, 13, 13, 1, 54);
    maxpool3s2_kernel<<<CDIV(128 * 256 * 36, 256), 256, 0, stream>>>(
        c5out, feat, 128, 256, 13, 13, 6, 6);

    // ---- head forward on feat (split-K GEMMs, partials in `part`) ----
    dim3 blk(16, 16);
    gemm64_nt_k<<<dim3(64, 2, 8), blk, 0, stream>>>(feat, w6, part, 128, 4096, 9216, 1152);
    reduce_parts<<<CDIV(128 * 4096, 256), 256, 0, stream>>>(part, b6, h1, 128 * 4096, 4096, 8, 1);
    gemm64_nt_k<<<dim3(64, 2, 8), blk, 0, stream>>>(h1, w7, part, 128, 4096, 4096, 512);
    reduce_parts<<<CDIV(128 * 4096, 256), 256, 0, stream>>>(part, b7, h2, 128 * 4096, 4096, 8, 1);
    gemm64_nt_k<<<dim3(2, 2, 8), blk, 0, stream>>>(h2, wc, part, 128, 100, 4096, 512);
    reduce_parts<<<CDIV(128 * 100, 256), 256, 0, stream>>>(part, bc, out0, 128 * 100, 100, 8, 0);

    // ---- analytic backward of sum(out[rows, gt]) w.r.t. feat ----
    g2m_kernel<<<CDIV(128 * 4096, 256), 256, 0, stream>>>(wc, gt, h2, g2m, 128, 4096);
    gemm64_nn_k<<<dim3(64, 2, 8), blk, 0, stream>>>(g2m, w7, part, 128, 4096, 4096, 512);
    reduce_parts<<<CDIV(128 * 4096, 256), 256, 0, stream>>>(part, nullptr, g1, 128 * 4096, 4096, 8, 0);
    relumask_kernel<<<CDIV(128 * 4096, 256), 256, 0, stream>>>(g1, h1, 128 * 4096);
    gemm64_nn_k<<<dim3(144, 2, 4), blk, 0, stream>>>(g1, w6, part, 128, 9216, 4096, 1024);
    reduce_parts<<<CDIV(128 * 9216, 256), 256, 0, stream>>>(part, nullptr, gf, 128 * 9216, 9216, 4, 0);

    // ---- RSC spatial mask ----
    spatial_mean_kernel<<<CDIV(128 * 36, 128), 128, 0, stream>>>(gf, sm, 128, 256, 36);
    rsc_mask_kernel<<<2, 64, 0, stream>>>(sm, u, mask, 128, 36, 12);

    // ---- masked head forward ----
    maskfeat_kernel<<<CDIV(128 * 9216, 256), 256, 0, stream>>>(feat, mask, featb, 128, 9216, 36);
    gemm64_nt_k<<<dim3(64, 2, 8), blk, 0, stream>>>(featb, w6, part, 128, 4096, 9216, 1152);
    reduce_parts<<<CDIV(128 * 4096, 256), 256, 0, stream>>>(part, b6, h1b, 128 * 4096, 4096, 8, 1);
    gemm64_nt_k<<<dim3(64, 2, 8), blk, 0, stream>>>(h1b, w7, part, 128, 4096, 4096, 512);
    reduce_parts<<<CDIV(128 * 4096, 256), 256, 0, stream>>>(part, b7, h2b, 128 * 4096, 4096, 8, 1);
    gemm64_nt_k<<<dim3(2, 2, 8), blk, 0, stream>>>(h2b, wc, part, 128, 100, 4096, 512);
    reduce_parts<<<CDIV(128 * 100, 256), 256, 0, stream>>>(part, bc, out1, 128 * 100, 100, 8, 0);

    // ---- cv, keep threshold (round(128/3)=43), final row select ----
    cv_kernel<<<1, 128, 0, stream>>>(out0, out1, gt, cv, 128, 100);
    final_select_kernel<<<1, 128, 0, stream>>>(cv, out0, out1, flag, out, 128, 100, 43);
}

// Round 3
// 2272.739 us; speedup vs baseline: 2.5000x; 1.2287x over previous
//
#include <hip/hip_runtime.h>

#define CDIV(a,b) (((a)+(b)-1)/(b))

typedef __attribute__((ext_vector_type(8))) short bf16x8;
typedef __attribute__((ext_vector_type(4))) float f32x4;

// pack fp32 -> {hi bf16 [31:16], lo bf16 [15:0]}, both RNE
__device__ __forceinline__ unsigned packsplit(float x) {
    union { float f; unsigned u; } a; a.f = x;
    unsigned r = a.u + 0x7fffu + ((a.u >> 16) & 1u);
    unsigned hi = r & 0xffff0000u;
    union { float f; unsigned u; } b; b.u = hi;
    float res = x - b.f;
    union { float f; unsigned u; } c; c.f = res;
    unsigned r2 = c.u + 0x7fffu + ((c.u >> 16) & 1u);
    return hi | (r2 >> 16);
}
__device__ __forceinline__ unsigned hipair(unsigned a, unsigned b){ return (a>>16)|(b&0xffff0000u); }
__device__ __forceinline__ unsigned lopair(unsigned a, unsigned b){ return (a&0xffffu)|(b<<16); }

// ---------------- elementwise fp32 -> packed split (with scale) ---------------
__global__ void pack_scale_kernel(const float* __restrict__ src, unsigned* __restrict__ dst,
                                  int n4, float scale)
{
    int i = blockIdx.x * blockDim.x + threadIdx.x;
    if (i >= n4) return;
    float4 v = ((const float4*)src)[i];
    uint4 o;
    o.x = packsplit(v.x * scale); o.y = packsplit(v.y * scale);
    o.z = packsplit(v.z * scale); o.w = packsplit(v.w * scale);
    ((uint4*)dst)[i] = o;
}

// ---------------- weight prepass: fp32 [G][cog][R] -> fragment-major slabs ---
// slab (g,cb,kt): 8192 shorts = [Ah 4096][Al 4096]; Ah[t*512 + ln*8 + e]
// (t=m-tile 0..7, ln=lane 0..63, e: k = kt*32 + (e<4 ? (ln>>4)*4+e : 16+(ln>>4)*4+e-4))
__global__ void wsplit_frag(const float* __restrict__ w, short* __restrict__ dst,
                            int G, int cog, int R, int CB, int niter)
{
    int idx = blockIdx.x * blockDim.x + threadIdx.x;
    int total = G * CB * niter * 512;
    if (idx >= total) return;
    int ln = idx & 63;
    int t  = (idx >> 6) & 7;
    int s  = idx >> 9;
    int kt = s % niter;
    int s2 = s / niter;
    int cb = s2 % CB;
    int g  = s2 / CB;
    int row = cb * 128 + t * 16 + (ln & 15);
    int qq = ln >> 4;
    bool rok = row < cog;
    const float* wr = w + (size_t)(g * cog + (rok ? row : 0)) * R;
    short hv[8], lv[8];
    #pragma unroll
    for (int e = 0; e < 8; ++e) {
        int k = kt * 32 + ((e < 4) ? (qq * 4 + e) : (16 + qq * 4 + e - 4));
        float x = (rok && k < R) ? wr[k] : 0.f;
        unsigned p = packsplit(x);
        hv[e] = (short)(p >> 16);
        lv[e] = (short)(p & 0xffffu);
    }
    short* sb = dst + (size_t)s * 8192 + t * 512 + ln * 8;
    *(short4*)(sb)     = make_short4(hv[0], hv[1], hv[2], hv[3]);
    *(short4*)(sb + 4) = make_short4(hv[4], hv[5], hv[6], hv[7]);
    short* sl = sb + 4096;
    *(short4*)(sl)     = make_short4(lv[0], lv[1], lv[2], lv[3]);
    *(short4*)(sl + 4) = make_short4(lv[4], lv[5], lv[6], lv[7]);
}

// ============ MFMA implicit-GEMM conv, packed-split inputs & weights =========
template<int KSZ, int STRIDE, int PAD, int OUTPACK>
__global__ __launch_bounds__(256, 2) void conv_mfma128(
    const unsigned* __restrict__ in, const short* __restrict__ wtr,
    const float* __restrict__ bs, void* __restrict__ outv,
    int N, int Cin, int Hin, int Win, int Cout, int groups,
    int Hout, int Wout, int CB, int niter)
{
    const int cig = Cin / groups, cog = Cout / groups;
    const int R = cig * KSZ * KSZ;
    const int HW = Hout * Wout;
    const int NSP = N * HW;
    const int g = blockIdx.z;
    const int cb = blockIdx.y;
    const int sp0 = blockIdx.x * 128;
    const int co0 = cb * 128;
    const int tid = threadIdx.x;
    const int lane = tid & 63;
    const int wid = tid >> 6;
    const int wr = wid >> 1, wc = wid & 1;

    __shared__ __align__(16) short Ah[4096];
    __shared__ __align__(16) short Al[4096];
    __shared__ __align__(16) short Bh[4096];
    __shared__ __align__(16) short Bl[4096];

    f32x4 acc[4][4];
    #pragma unroll
    for (int i = 0; i < 4; ++i)
        #pragma unroll
        for (int j = 0; j < 4; ++j)
            acc[i][j] = (f32x4){0.f, 0.f, 0.f, 0.f};

    const int s_ = tid & 127;
    const int qpair = tid >> 7;
    const int spx = sp0 + s_;
    const bool xok = spx < NSP;
    int xn = 0, xho = 0, xwo = 0;
    if (xok) { xn = spx / HW; int pp = spx - xn * HW; xho = pp / Wout; xwo = pp - xho * Wout; }
    const unsigned* inb = in + ((size_t)xn * Cin + (size_t)g * cig) * Hin * Win;
    const int hi0 = xho * STRIDE - PAD, wi0 = xwo * STRIDE - PAD;
    const int bnt = s_ >> 4, bnl = s_ & 15;
    const int lnE = bnl + 32 * qpair;
    const int lnO = lnE + 16;

    const short* slab0 = wtr + (size_t)((g * CB + cb) * niter) * 8192;

    for (int it = 0; it < niter; ++it) {
        const int r0 = it * 32;
        {
            const uint4* src = (const uint4*)(slab0 + (size_t)it * 8192);
            uint4 a0 = src[tid], a1 = src[tid + 256];
            uint4 c0 = src[tid + 512], c1 = src[tid + 768];
            ((uint4*)Ah)[tid] = a0; ((uint4*)Ah)[tid + 256] = a1;
            ((uint4*)Al)[tid] = c0; ((uint4*)Al)[tid + 256] = c1;
        }
        {
            const int kA = r0 + qpair * 8;
            int ciA, khA, kwA, ciB, khB, kwB;
            { int kk = kA;      ciA = kk / (KSZ*KSZ); int rem = kk - ciA*(KSZ*KSZ); khA = rem / KSZ; kwA = rem - khA*KSZ; }
            { int kk = kA + 16; ciB = kk / (KSZ*KSZ); int rem = kk - ciB*(KSZ*KSZ); khB = rem / KSZ; kwB = rem - khB*KSZ; }
            unsigned uA[8], uB[8];
            #pragma unroll
            for (int e = 0; e < 8; ++e) {
                {
                    int hh = hi0 + khA, ww = wi0 + kwA;
                    unsigned v = 0u;
                    if (xok && (kA + e) < R && (unsigned)hh < (unsigned)Hin && (unsigned)ww < (unsigned)Win)
                        v = inb[(size_t)(ciA * Hin + hh) * Win + ww];
                    uA[e] = v;
                    if (++kwA == KSZ) { kwA = 0; if (++khA == KSZ) { khA = 0; ++ciA; } }
                }
                {
                    int hh = hi0 + khB, ww = wi0 + kwB;
                    unsigned v = 0u;
                    if (xok && (kA + 16 + e) < R && (unsigned)hh < (unsigned)Hin && (unsigned)ww < (unsigned)Win)
                        v = inb[(size_t)(ciB * Hin + hh) * Win + ww];
                    uB[e] = v;
                    if (++kwB == KSZ) { kwB = 0; if (++khB == KSZ) { khB = 0; ++ciB; } }
                }
            }
            uint4 d;
            d.x = hipair(uA[0], uA[1]); d.y = hipair(uA[2], uA[3]);
            d.z = hipair(uB[0], uB[1]); d.w = hipair(uB[2], uB[3]);
            ((uint4*)Bh)[bnt * 64 + lnE] = d;
            d.x = hipair(uA[4], uA[5]); d.y = hipair(uA[6], uA[7]);
            d.z = hipair(uB[4], uB[5]); d.w = hipair(uB[6], uB[7]);
            ((uint4*)Bh)[bnt * 64 + lnO] = d;
            d.x = lopair(uA[0], uA[1]); d.y = lopair(uA[2], uA[3]);
            d.z = lopair(uB[0], uB[1]); d.w = lopair(uB[2], uB[3]);
            ((uint4*)Bl)[bnt * 64 + lnE] = d;
            d.x = lopair(uA[4], uA[5]); d.y = lopair(uA[6], uA[7]);
            d.z = lopair(uB[4], uB[5]); d.w = lopair(uB[6], uB[7]);
            ((uint4*)Bl)[bnt * 64 + lnO] = d;
        }
        __syncthreads();
        {
            bf16x8 fah[4], fal[4], fbh[4], fbl[4];
            #pragma unroll
            for (int mi = 0; mi < 4; ++mi) {
                int off = (wr * 4 + mi) * 512 + lane * 8;
                fah[mi] = *(const bf16x8*)(Ah + off);
                fal[mi] = *(const bf16x8*)(Al + off);
            }
            #pragma unroll
            for (int ni = 0; ni < 4; ++ni) {
                int off = (wc * 4 + ni) * 512 + lane * 8;
                fbh[ni] = *(const bf16x8*)(Bh + off);
                fbl[ni] = *(const bf16x8*)(Bl + off);
            }
            #pragma unroll
            for (int mi = 0; mi < 4; ++mi)
                #pragma unroll
                for (int ni = 0; ni < 4; ++ni) {
                    acc[mi][ni] = __builtin_amdgcn_mfma_f32_16x16x32_bf16(fah[mi], fbh[ni], acc[mi][ni], 0, 0, 0);
                    acc[mi][ni] = __builtin_amdgcn_mfma_f32_16x16x32_bf16(fah[mi], fbl[ni], acc[mi][ni], 0, 0, 0);
                    acc[mi][ni] = __builtin_amdgcn_mfma_f32_16x16x32_bf16(fal[mi], fbh[ni], acc[mi][ni], 0, 0, 0);
                }
        }
        __syncthreads();
    }

    const int colc = lane & 15;
    const int rowb = (lane >> 4) * 4;
    #pragma unroll
    for (int ni = 0; ni < 4; ++ni) {
        int sp = sp0 + (wc * 4 + ni) * 16 + colc;
        if (sp >= NSP) continue;
        int n = sp / HW; int pp = sp - n * HW;
        #pragma unroll
        for (int mi = 0; mi < 4; ++mi) {
            #pragma unroll
            for (int j = 0; j < 4; ++j) {
                int cop = co0 + (wr * 4 + mi) * 16 + rowb + j;
                if (cop >= cog) continue;
                int co = g * cog + cop;
                float v = fmaxf(bs[co] + acc[mi][ni][j], 0.f);
                size_t oi = ((size_t)n * Cout + co) * HW + pp;
                if (OUTPACK) ((unsigned*)outv)[oi] = packsplit(v);
                else         ((float*)outv)[oi] = v;
            }
        }
    }
}

// ============ MFMA head GEMM: part[kz] += act[128,krange] @ W ================
// act: packed u32 [128,K] row-major. W fp32: NT -> [N,K]; NN -> [K,N].
// grid (1, N/128, KZ); N%128==0, kchunk%32==0, K%kchunk==0. 256 thr, 4 waves.
template<int WNN>
__global__ __launch_bounds__(256, 2) void gemm_mfma_k(
    const unsigned* __restrict__ act, const float* __restrict__ W,
    float* __restrict__ part, int N, int K, int kchunk)
{
    const int n0 = blockIdx.y * 128;
    const int kz = blockIdx.z;
    const int kbeg = kz * kchunk;
    const int kend = kbeg + kchunk;
    const int tid = threadIdx.x;
    const int lane = tid & 63;
    const int wid = tid >> 6;
    const int wr = wid >> 1, wc2 = wid & 1;

    __shared__ __align__(16) short Ah[4096];
    __shared__ __align__(16) short Al[4096];
    __shared__ __align__(16) short Bh[4096];
    __shared__ __align__(16) short Bl[4096];

    f32x4 acc[4][4];
    #pragma unroll
    for (int i = 0; i < 4; ++i)
        #pragma unroll
        for (int j = 0; j < 4; ++j)
            acc[i][j] = (f32x4){0.f, 0.f, 0.f, 0.f};

    // staging map: rr = row (0..127), kq = 0/16
    const int rr = tid >> 1;
    const int kq = (tid & 1) * 16;
    const int dsoff = (rr >> 4) * 512 + (rr & 15) * 8 + (kq ? 4 : 0);
    short* dAh = Ah + dsoff; short* dAl = Al + dsoff;
    short* dBh = Bh + dsoff; short* dBl = Bl + dsoff;
    const unsigned* actrow = act + (size_t)rr * K + kq;

    for (int k0 = kbeg; k0 < kend; k0 += 32) {
        // ---- weights fp32 -> split -> Ah/Al (fragment-major)
        {
            float wv[16];
            if (!WNN) {
                const float* src = W + (size_t)(n0 + rr) * K + k0 + kq;
                #pragma unroll
                for (int q4 = 0; q4 < 4; ++q4) {
                    float4 v = *(const float4*)(src + q4 * 4);
                    wv[q4*4+0] = v.x; wv[q4*4+1] = v.y; wv[q4*4+2] = v.z; wv[q4*4+3] = v.w;
                }
            } else {
                const float* src = W + (size_t)(k0 + kq) * N + n0 + rr;
                #pragma unroll
                for (int j = 0; j < 16; ++j) wv[j] = src[(size_t)j * N];
            }
            #pragma unroll
            for (int q4 = 0; q4 < 4; ++q4) {
                unsigned p0 = packsplit(wv[q4*4+0]), p1 = packsplit(wv[q4*4+1]);
                unsigned p2 = packsplit(wv[q4*4+2]), p3 = packsplit(wv[q4*4+3]);
                *(short4*)(dAh + q4*128) = make_short4((short)(p0>>16),(short)(p1>>16),(short)(p2>>16),(short)(p3>>16));
                *(short4*)(dAl + q4*128) = make_short4((short)(p0&0xffff),(short)(p1&0xffff),(short)(p2&0xffff),(short)(p3&0xffff));
            }
        }
        // ---- activations packed u32 -> Bh/Bl
        {
            const uint4* s = (const uint4*)(actrow + k0);
            #pragma unroll
            for (int q4 = 0; q4 < 4; ++q4) {
                uint4 u = s[q4];
                *(short4*)(dBh + q4*128) = make_short4((short)(u.x>>16),(short)(u.y>>16),(short)(u.z>>16),(short)(u.w>>16));
                *(short4*)(dBl + q4*128) = make_short4((short)(u.x&0xffff),(short)(u.y&0xffff),(short)(u.z&0xffff),(short)(u.w&0xffff));
            }
        }
        __syncthreads();
        {
            bf16x8 fah[4], fal[4], fbh[4], fbl[4];
            #pragma unroll
            for (int mi = 0; mi < 4; ++mi) {
                int off = (wr * 4 + mi) * 512 + lane * 8;
                fah[mi] = *(const bf16x8*)(Ah + off);
                fal[mi] = *(const bf16x8*)(Al + off);
            }
            #pragma unroll
            for (int ni = 0; ni < 4; ++ni) {
                int off = (wc2 * 4 + ni) * 512 + lane * 8;
                fbh[ni] = *(const bf16x8*)(Bh + off);
                fbl[ni] = *(const bf16x8*)(Bl + off);
            }
            #pragma unroll
            for (int mi = 0; mi < 4; ++mi)
                #pragma unroll
                for (int ni = 0; ni < 4; ++ni) {
                    acc[mi][ni] = __builtin_amdgcn_mfma_f32_16x16x32_bf16(fah[mi], fbh[ni], acc[mi][ni], 0, 0, 0);
                    acc[mi][ni] = __builtin_amdgcn_mfma_f32_16x16x32_bf16(fah[mi], fbl[ni], acc[mi][ni], 0, 0, 0);
                    acc[mi][ni] = __builtin_amdgcn_mfma_f32_16x16x32_bf16(fal[mi], fbh[ni], acc[mi][ni], 0, 0, 0);
                }
        }
        __syncthreads();
    }

    // epilogue: part[kz][m*N + n]; C row = n (A/weights), col = m (B/act)
    const int colc = lane & 15;
    const int rowb = (lane >> 4) * 4;
    float* pout = part + (size_t)kz * 128 * N;
    #pragma unroll
    for (int ni = 0; ni < 4; ++ni) {
        int m = (wc2 * 4 + ni) * 16 + colc;
        #pragma unroll
        for (int mi = 0; mi < 4; ++mi) {
            #pragma unroll
            for (int j = 0; j < 4; ++j) {
                int n = n0 + (wr * 4 + mi) * 16 + rowb + j;
                pout[(size_t)m * N + n] = acc[mi][ni][j];
            }
        }
    }
}

// ============ split-K NT GEMM (fp32, small wc head only) =====================
__global__ __launch_bounds__(256) void gemm64_nt_k(
    const float* __restrict__ A, const float* __restrict__ W,
    float* __restrict__ part, int M, int N, int K, int kchunk)
{
    const int tx = threadIdx.x, ty = threadIdx.y;
    const int tid = ty * 16 + tx;
    const int m0 = blockIdx.y * 64, n0 = blockIdx.x * 64;
    const int kz = blockIdx.z;
    const int kbeg = kz * kchunk;
    const int kend = min(K, kbeg + kchunk);
    __shared__ float As[16][68], Bs[16][68];
    float acc[4][4] = {};

    const int lr = tid >> 2;
    const int lk4 = (tid & 3) * 4;
    const bool arow_ok = (m0 + lr) < M;
    const bool wrow_ok = (n0 + lr) < N;
    const float* arow = A + (size_t)(m0 + lr) * K;
    const float* wrow = W + (size_t)(n0 + lr) * K;

    for (int k0 = kbeg; k0 < kend; k0 += 16) {
        if (arow_ok && (k0 + lk4 + 3) < kend) {
            float4 v = *(const float4*)(arow + k0 + lk4);
            As[lk4 + 0][lr] = v.x; As[lk4 + 1][lr] = v.y; As[lk4 + 2][lr] = v.z; As[lk4 + 3][lr] = v.w;
        } else {
            #pragma unroll
            for (int q = 0; q < 4; ++q) {
                int k = k0 + lk4 + q;
                As[lk4 + q][lr] = (arow_ok && k < kend) ? arow[k] : 0.f;
            }
        }
        if (wrow_ok && (k0 + lk4 + 3) < kend) {
            float4 v = *(const float4*)(wrow + k0 + lk4);
            Bs[lk4 + 0][lr] = v.x; Bs[lk4 + 1][lr] = v.y; Bs[lk4 + 2][lr] = v.z; Bs[lk4 + 3][lr] = v.w;
        } else {
            #pragma unroll
            for (int q = 0; q < 4; ++q) {
                int k = k0 + lk4 + q;
                Bs[lk4 + q][lr] = (wrow_ok && k < kend) ? wrow[k] : 0.f;
            }
        }
        __syncthreads();
        #pragma unroll
        for (int kk = 0; kk < 16; ++kk) {
            float a[4], b[4];
            *(float4*)a = *(const float4*)&As[kk][ty * 4];
            *(float4*)b = *(const float4*)&Bs[kk][tx * 4];
            #pragma unroll
            for (int i = 0; i < 4; ++i)
                #pragma unroll
                for (int j = 0; j < 4; ++j)
                    acc[i][j] = fmaf(a[i], b[j], acc[i][j]);
        }
        __syncthreads();
    }
    float* pout = part + (size_t)kz * M * N;
    #pragma unroll
    for (int i = 0; i < 4; ++i) {
        int row = m0 + ty * 4 + i;
        if (row >= M) continue;
        #pragma unroll
        for (int j = 0; j < 4; ++j) {
            int col = n0 + tx * 4 + j;
            if (col >= N) continue;
            pout[(size_t)row * N + col] = acc[i][j];
        }
    }
}

// ------- split-K reduce, fused bias + relu; optional fp32 and packed outs -----
__global__ void reduce_parts(const float* __restrict__ part, const float* __restrict__ bias,
                             float* __restrict__ outf, unsigned* __restrict__ pk,
                             int MN, int N, int P, int relu)
{
    int idx = blockIdx.x * blockDim.x + threadIdx.x;
    if (idx >= MN) return;
    float s = 0.f;
    for (int p = 0; p < P; ++p) s += part[(size_t)p * MN + idx];
    if (bias) s += bias[idx % N];
    if (relu) s = fmaxf(s, 0.f);
    if (outf) outf[idx] = s;
    if (pk) pk[idx] = packsplit(s);
}

// ---------------- maxpool 3x3 stride 2 ----------------------------------------
__global__ void maxpool3s2_kernel(const float* __restrict__ in, float* __restrict__ out,
                                  int N, int C, int Hin, int Win, int Hout, int Wout)
{
    int idx = blockIdx.x * blockDim.x + threadIdx.x;
    int total = N * C * Hout * Wout;
    if (idx >= total) return;
    int wo = idx % Wout; int t = idx / Wout;
    int ho = t % Hout; t /= Hout;
    int c = t % C; int n = t / C;
    const float* ip = in + ((size_t)n * C + c) * Hin * Win;
    int h0 = ho * 2, w0 = wo * 2;
    float m = -1e30f;
    for (int dh = 0; dh < 3; ++dh)
        for (int dw = 0; dw < 3; ++dw)
            m = fmaxf(m, ip[(h0 + dh) * Win + (w0 + dw)]);
    out[idx] = m;
}

// ------- LRN (n=5) in-place, output written as packed {hi,lo} u32 -------------
__global__ void lrn_pack_kernel(float* __restrict__ x, int N, int C, int HW)
{
    int idx = blockIdx.x * blockDim.x + threadIdx.x;
    int total = N * HW;
    if (idx >= total) return;
    int p = idx % HW; int n = idx / HW;
    float* base = x + (size_t)n * C * HW + p;
    unsigned* ubase = (unsigned*)base;
    const float an = 1e-4f / 5.f;
    float r0 = 0.f, r1 = 0.f, r2, r3, r4;
    r2 = base[0];
    r3 = (C > 1) ? base[(size_t)HW] : 0.f;
    r4 = (C > 2) ? base[(size_t)2 * HW] : 0.f;
    float s = r2 * r2 + r3 * r3 + r4 * r4;
    for (int c = 0; c < C; ++c) {
        float y = r2 / powf(1.f + an * s, 0.75f);
        ubase[(size_t)c * HW] = packsplit(y);
        s -= r0 * r0;
        r0 = r1; r1 = r2; r2 = r3; r3 = r4;
        r4 = (c + 3 < C) ? base[(size_t)(c + 3) * HW] : 0.f;
        s += r4 * r4;
    }
}

// ---------------- backward helpers --------------------------------------------
__global__ void g2m_pack_kernel(const float* __restrict__ wc, const int* __restrict__ gt,
                                const float* __restrict__ h2, unsigned* __restrict__ g2mp,
                                int B, int D)
{
    int idx = blockIdx.x * blockDim.x + threadIdx.x;
    if (idx >= B * D) return;
    int b = idx / D, i = idx % D;
    g2mp[idx] = packsplit((h2[idx] > 0.f) ? wc[(size_t)gt[b] * D + i] : 0.f);
}

__global__ void relupack_kernel(const float* __restrict__ g, const float* __restrict__ h,
                                unsigned* __restrict__ gp, int n)
{
    int idx = blockIdx.x * blockDim.x + threadIdx.x;
    if (idx >= n) return;
    gp[idx] = packsplit((h[idx] > 0.f) ? g[idx] : 0.f);
}

__global__ void spatial_mean_kernel(const float* __restrict__ gf, float* __restrict__ sm,
                                    int B, int C, int HW)
{
    int idx = blockIdx.x * blockDim.x + threadIdx.x;
    if (idx >= B * HW) return;
    int b = idx / HW, p = idx % HW;
    const float* g = gf + (size_t)b * C * HW + p;
    float s = 0.f;
    for (int c = 0; c < C; ++c) s += g[(size_t)c * HW];
    sm[idx] = s / (float)C;
}

// ------- RSC spatial mask: one block per b, LDS + rank select (exact) ---------
__global__ void rsc_mask_kernel(const float* __restrict__ sm, const float* __restrict__ u,
                                float* __restrict__ mask, int HW, int drop)
{
    int b = blockIdx.x;
    int p = threadIdx.x;
    __shared__ float s[64], uu[64];
    __shared__ float th;
    if (p < HW) { s[p] = sm[(size_t)b * HW + p]; uu[p] = u[(size_t)b * HW + p]; }
    __syncthreads();
    if (p < HW) {
        float v = s[p];
        int cg = 0, ce = 0;
        for (int q = 0; q < HW; ++q) { cg += (s[q] > v); ce += (s[q] == v); }
        if (cg <= drop && drop < cg + ce) th = v;  // unique value; benign multi-write
    }
    __syncthreads();
    if (p < HW) {
        // sc[p] = candidate ? u : -1; chosen = top-`drop` by (sc desc, index asc)
        float v = (s[p] >= th) ? uu[p] : -1.0f;
        int rank = 0;
        for (int q = 0; q < HW; ++q) {
            float w = (s[q] >= th) ? uu[q] : -1.0f;
            rank += (w > v) || (w == v && q < p);
        }
        mask[(size_t)b * HW + p] = (rank < drop) ? 0.f : 1.f;
    }
}

__global__ void maskfeat_pack_kernel(const float* __restrict__ feat, const float* __restrict__ mask,
                                     unsigned* __restrict__ featbp, int B, int CHW, int HW)
{
    int idx = blockIdx.x * blockDim.x + threadIdx.x;
    if (idx >= B * CHW) return;
    int b = idx / CHW, j = idx % CHW;
    featbp[idx] = packsplit(feat[idx] * mask[(size_t)b * HW + (j % HW)]);
}

__global__ void cv_kernel(const float* __restrict__ out0, const float* __restrict__ out1,
                          const int* __restrict__ gt, float* __restrict__ cv, int B, int NCc)
{
    int b = blockIdx.x * blockDim.x + threadIdx.x;
    if (b >= B) return;
    const float* a = out0 + (size_t)b * NCc;
    const float* c = out1 + (size_t)b * NCc;
    int g = gt[b];
    float m0 = -1e30f, m1 = -1e30f;
    for (int i = 0; i < NCc; ++i) { m0 = fmaxf(m0, a[i]); m1 = fmaxf(m1, c[i]); }
    float s0 = 0.f, s1 = 0.f;
    for (int i = 0; i < NCc; ++i) { s0 += expf(a[i] - m0); s1 += expf(c[i] - m1); }
    float pb = expf(a[g] - m0) / s0;
    float pa = expf(c[g] - m1) / s1;
    cv[b] = fmaxf(pb - pa - 1e-4f, 0.f);
}

__global__ void final_select_kernel(const float* __restrict__ cv, const float* __restrict__ out0,
                                    const float* __restrict__ out1, const int* __restrict__ flag,
                                    float* __restrict__ out, int B, int NCc, int kidx)
{
    __shared__ float thfg;
    int b = threadIdx.x;
    float v = cv[b];
    int cg = 0, ce = 0;
    for (int j = 0; j < B; ++j) { float w = cv[j]; cg += (w > v); ce += (w == v); }
    if (cg <= kidx && kidx < cg + ce) thfg = v;
    __syncthreads();
    bool keep = !(v > thfg);
    if (*flag == 0) keep = true;
    const float* src = keep ? out0 : out1;
    for (int c = 0; c < NCc; ++c)
        out[(size_t)b * NCc + c] = src[(size_t)b * NCc + c];
}

// ------------------------------------------------------------------------------
extern "C" void kernel_launch(void* const* d_in, const int* in_sizes, int n_in,
                              void* d_out, int out_size, void* d_ws, size_t ws_size,
                              hipStream_t stream) {
    const float* x   = (const float*)d_in[0];
    const int*   gt  = (const int*)d_in[1];
    const float* u   = (const float*)d_in[2];
    const int*   flag= (const int*)d_in[3];
    const float* w1  = (const float*)d_in[4];  const float* b1 = (const float*)d_in[5];
    const float* w2  = (const float*)d_in[6];  const float* b2 = (const float*)d_in[7];
    const float* w3  = (const float*)d_in[8];  const float* b3 = (const float*)d_in[9];
    const float* w4  = (const float*)d_in[10]; const float* b4 = (const float*)d_in[11];
    const float* w5  = (const float*)d_in[12]; const float* b5 = (const float*)d_in[13];
    const float* w6  = (const float*)d_in[14]; const float* b6 = (const float*)d_in[15];
    const float* w7  = (const float*)d_in[16]; const float* b7 = (const float*)d_in[17];
    const float* wc  = (const float*)d_in[18]; const float* bc = (const float*)d_in[19];
    float* out = (float*)d_out;
    (void)ws_size; (void)in_sizes; (void)n_in; (void)out_size;

    // ---- workspace layout (4B units) ----
    float* w = (float*)d_ws;
    float* p1   = w;                                 // 8,957,952
    float* p2   = p1 + (size_t)8957952;              // 5,537,792
    float* wtrF = p2 + (size_t)5537792;              // 2,572,288 (short slabs)
    float* Br   = wtrF + (size_t)2572288;            // 23,887,872 reused region
    short* wtrS = (short*)wtrF;

    float*    cbuf1 = Br;
    unsigned* xs    = (unsigned*)(Br + (size_t)9292800);
    float* cbuf2 = Br;
    unsigned* c3s  = (unsigned*)Br;                  // 8,306,688
    unsigned* c4s  = (unsigned*)(Br + (size_t)8306688); // 8,306,688
    float* c5out   = Br;                             // 5,537,792 (over dead c3s)
    float* part    = Br + (size_t)8306688;           // over dead c4s; max 4,718,592
    // head buffers after c3s+c4s (avail 7,274,496 floats)
    float*    feat  = Br + (size_t)16613376;         // 1,179,648
    unsigned* fp_sh = (unsigned*)(feat + 1179648);   // 1,179,648 (featp, then featbp)
    float*    h1    = (float*)(fp_sh + 1179648);     // 524,288
    unsigned* h1p   = (unsigned*)(h1 + 524288);      // 524,288
    float*    h2    = (float*)(h1p + 524288);        // 524,288
    float*    sA    = h2 + 524288;                   // 524,288 (g1, then h2b)
    unsigned* sB    = (unsigned*)(sA + 524288);      // 524,288 (g2mp, then h1bp)
    unsigned* g1p   = sB + 524288;                   // 524,288
    float*    gf    = (float*)(g1p + 524288);        // 1,179,648
    float*    out0  = gf + 1179648;                  // 12,800
    float*    out1  = out0 + 12800;
    float*    sm    = out1 + 12800;                  // 4,608
    float*    mask  = sm + 4608;
    float*    cv    = mask + 4608;

    // conv weight slab offsets (shorts)
    const size_t o1 = 0;
    const size_t o2 = 98304;
    const size_t o3 = 720896;
    const size_t o4 = 2490368;
    const size_t o5 = 4259840;

    // ---- conv weight prepass ----
    wsplit_frag<<<CDIV(1*1*12*512, 256), 256, 0, stream>>>(w1, wtrS + o1, 1,  96,  363, 1, 12);
    wsplit_frag<<<CDIV(2*1*38*512, 256), 256, 0, stream>>>(w2, wtrS + o2, 2, 128, 1200, 1, 38);
    wsplit_frag<<<CDIV(1*3*72*512, 256), 256, 0, stream>>>(w3, wtrS + o3, 1, 384, 2304, 3, 72);
    wsplit_frag<<<CDIV(2*2*54*512, 256), 256, 0, stream>>>(w4, wtrS + o4, 2, 192, 1728, 2, 54);
    wsplit_frag<<<CDIV(2*1*54*512, 256), 256, 0, stream>>>(w5, wtrS + o5, 2, 128, 1728, 1, 54);

    // ---- layer 1 ----
    for (int cs = 0; cs < 128; cs += 32) {
        pack_scale_kernel<<<CDIV(1236696, 256), 256, 0, stream>>>(
            x + (size_t)cs * 154587, xs, 1236696, 57.6f);
        conv_mfma128<11, 4, 0, 0><<<dim3(757, 1, 1), 256, 0, stream>>>(
            xs, wtrS + o1, b1, cbuf1, 32, 3, 227, 227, 96, 1, 55, 55, 1, 12);
        maxpool3s2_kernel<<<CDIV(32 * 96 * 729, 256), 256, 0, stream>>>(
            cbuf1, p1 + (size_t)cs * 96 * 729, 32, 96, 55, 55, 27, 27);
    }
    lrn_pack_kernel<<<CDIV(128 * 729, 256), 256, 0, stream>>>(p1, 128, 96, 729);

    // ---- layer 2 ----
    conv_mfma128<5, 1, 2, 0><<<dim3(729, 1, 2), 256, 0, stream>>>(
        (const unsigned*)p1, wtrS + o2, b2, cbuf2, 128, 96, 27, 27, 256, 2, 27, 27, 1, 38);
    maxpool3s2_kernel<<<CDIV(128 * 256 * 169, 256), 256, 0, stream>>>(
        cbuf2, p2, 128, 256, 27, 27, 13, 13);
    lrn_pack_kernel<<<CDIV(128 * 169, 256), 256, 0, stream>>>(p2, 128, 256, 169);

    // ---- conv3/4/5 + pool ----
    conv_mfma128<3, 1, 1, 1><<<dim3(169, 3, 1), 256, 0, stream>>>(
        (const unsigned*)p2, wtrS + o3, b3, c3s, 128, 256, 13, 13, 384, 1, 13, 13, 3, 72);
    conv_mfma128<3, 1, 1, 1><<<dim3(169, 2, 2), 256, 0, stream>>>(
        c3s, wtrS + o4, b4, c4s, 128, 384, 13, 13, 384, 2, 13, 13, 2, 54);
    conv_mfma128<3, 1, 1, 0><<<dim3(169, 1, 2), 256, 0, stream>>>(
        c4s, wtrS + o5, b5, c5out, 128, 384, 13, 13, 256, 2, 13, 13, 1, 54);
    maxpool3s2_kernel<<<CDIV(128 * 256 * 36, 256), 256, 0, stream>>>(
        c5out, feat, 128, 256, 13, 13, 6, 6);

    // ---- head forward (MFMA GEMMs) ----
    pack_scale_kernel<<<CDIV(294912, 256), 256, 0, stream>>>(feat, fp_sh, 294912, 1.f);
    gemm_mfma_k<0><<<dim3(1, 32, 8), 256, 0, stream>>>(fp_sh, w6, part, 4096, 9216, 1152);
    reduce_parts<<<CDIV(128 * 4096, 256), 256, 0, stream>>>(part, b6, h1, h1p, 128 * 4096, 4096, 8, 1);
    gemm_mfma_k<0><<<dim3(1, 32, 8), 256, 0, stream>>>(h1p, w7, part, 4096, 4096, 512);
    reduce_parts<<<CDIV(128 * 4096, 256), 256, 0, stream>>>(part, b7, h2, nullptr, 128 * 4096, 4096, 8, 1);
    gemm64_nt_k<<<dim3(2, 2, 8), dim3(16, 16), 0, stream>>>(h2, wc, part, 128, 100, 4096, 512);
    reduce_parts<<<CDIV(128 * 100, 256), 256, 0, stream>>>(part, bc, out0, nullptr, 128 * 100, 100, 8, 0);

    // ---- analytic backward ----
    g2m_pack_kernel<<<CDIV(128 * 4096, 256), 256, 0, stream>>>(wc, gt, h2, sB, 128, 4096);
    gemm_mfma_k<1><<<dim3(1, 32, 8), 256, 0, stream>>>(sB, w7, part, 4096, 4096, 512);
    reduce_parts<<<CDIV(128 * 4096, 256), 256, 0, stream>>>(part, nullptr, sA, nullptr, 128 * 4096, 4096, 8, 0);
    relupack_kernel<<<CDIV(128 * 4096, 256), 256, 0, stream>>>(sA, h1, g1p, 128 * 4096);
    gemm_mfma_k<1><<<dim3(1, 72, 4), 256, 0, stream>>>(g1p, w6, part, 9216, 4096, 1024);
    reduce_parts<<<CDIV(128 * 9216, 256), 256, 0, stream>>>(part, nullptr, gf, nullptr, 128 * 9216, 9216, 4, 0);

    // ---- RSC spatial mask ----
    spatial_mean_kernel<<<CDIV(128 * 36, 128), 128, 0, stream>>>(gf, sm, 128, 256, 36);
    rsc_mask_kernel<<<128, 64, 0, stream>>>(sm, u, mask, 36, 12);

    // ---- masked head forward ----
    maskfeat_pack_kernel<<<CDIV(128 * 9216, 256), 256, 0, stream>>>(feat, mask, fp_sh, 128, 9216, 36);
    gemm_mfma_k<0><<<dim3(1, 32, 8), 256, 0, stream>>>(fp_sh, w6, part, 4096, 9216, 1152);
    reduce_parts<<<CDIV(128 * 4096, 256), 256, 0, stream>>>(part, b6, nullptr, sB, 128 * 4096, 4096, 8, 1);
    gemm_mfma_k<0><<<dim3(1, 32, 8), 256, 0, stream>>>(sB, w7, part, 4096, 4096, 512);
    reduce_parts<<<CDIV(128 * 4096, 256), 256, 0, stream>>>(part, b7, sA, nullptr, 128 * 4096, 4096, 8, 1);
    gemm64_nt_k<<<dim3(2, 2, 8), dim3(16, 16), 0, stream>>>(sA, wc, part, 128, 100, 4096, 512);
    reduce_parts<<<CDIV(128 * 100, 256), 256, 0, stream>>>(part, bc, out1, nullptr, 128 * 100, 100, 8, 0);

    // ---- cv + final select ----
    cv_kernel<<<1, 128, 0, stream>>>(out0, out1, gt, cv, 128, 100);
    final_select_kernel<<<1, 128, 0, stream>>>(cv, out0, out1, flag, out, 128, 100, 43);
}